// Round 10
// baseline (497.108 us; speedup 1.0000x reference)
//
#include <hip/hip_runtime.h>
#include <hip/hip_bf16.h>

#define N_NODES 100000
#define N_EDGES 1600000
#define N_FEAT 128
#define HID 64
#define N_GRAPHS 64
#define N_OUT 10
#define SCAN_B 1024
#define NBLK ((N_NODES + SCAN_B - 1) / SCAN_B)  // 98
#define NBUCK 64
#define RANGE64 ((N_NODES + NBUCK - 1) / NBUCK)  // 1563
#define CAP 40000                                 // mean 25000/bucket, >60 sigma headroom

typedef __attribute__((ext_vector_type(8))) short bf8_t;   // 8 bf16 in 4 VGPRs
typedef __attribute__((ext_vector_type(4))) float f4_t;    // MFMA accumulator

__device__ __forceinline__ short f2bf(float f) {
    __hip_bfloat16 h = __float2bfloat16(f);
    return *(short*)&h;
}
__device__ __forceinline__ float bf2f(unsigned short u) {
    unsigned v = ((unsigned)u) << 16;
    return __builtin_bit_cast(float, v);
}
__device__ __forceinline__ short tobf(float v) { return f2bf(v); }
__device__ __forceinline__ short tobf(unsigned short v) { return (short)v; }

// ---------- index dtype probe: 1 = int64 storage, 0 = int32 storage ----------
__global__ void k_detect(const int* raw, int* flag) {
    __shared__ int any;
    if (threadIdx.x == 0) any = 0;
    __syncthreads();
    int v = raw[2 * threadIdx.x + 1] | raw[2 * (threadIdx.x + 256) + 1] |
            raw[2 * (threadIdx.x + 512) + 1] | raw[2 * (threadIdx.x + 768) + 1];
    if (v != 0) any = 1;  // benign race
    __syncthreads();
    if (threadIdx.x == 0) *flag = (any == 0) ? 1 : 0;
}

__device__ __forceinline__ int ldidx(const int* raw, int f, size_t i) {
    return f ? raw[2 * i] : raw[i];
}

// ---------- phase 1: bin edges into 64 col-range buckets (LDS-aggregated cursors) ----------
__global__ __launch_bounds__(256) void k_bucket(const int* ei, const int* flag,
                                                int2* pairs, int* cnt) {
    __shared__ int lcnt[NBUCK];
    __shared__ int gbase[NBUCK];
    int f = *flag;
    if (threadIdx.x < NBUCK) lcnt[threadIdx.x] = 0;
    __syncthreads();
    int base = blockIdx.x * 2048;
    int r[8], lpos[8], c[8], s[8];
#pragma unroll
    for (int i = 0; i < 8; i++) {
        int e = base + i * 256 + threadIdx.x;
        r[i] = -1;
        if (e < N_EDGES) {
            c[i] = ldidx(ei, f, (size_t)N_EDGES + e);
            s[i] = ldidx(ei, f, (size_t)e);
            if ((unsigned)c[i] < N_NODES && (unsigned)s[i] < N_NODES) {
                r[i] = c[i] / RANGE64;
                lpos[i] = atomicAdd(&lcnt[r[i]], 1);
            }
        }
    }
    __syncthreads();
    if (threadIdx.x < NBUCK && lcnt[threadIdx.x] > 0)
        gbase[threadIdx.x] = atomicAdd(&cnt[threadIdx.x], lcnt[threadIdx.x]);
    __syncthreads();
#pragma unroll
    for (int i = 0; i < 8; i++) {
        if (r[i] >= 0) {
            int p = gbase[r[i]] + lpos[i];
            if (p < CAP) {
                int2 v; v.x = c[i]; v.y = s[i];
                pairs[(size_t)r[i] * CAP + p] = v;
            }
        }
    }
}

// ---------- in-degree from buckets (bucket-affine: blockIdx&63 = bucket) ----------
__global__ __launch_bounds__(256) void k_deg2(const int2* pairs, const int* cnt, int* indeg) {
    int b = blockIdx.x & 63;
    int sub = blockIdx.x >> 6;  // 0..7
    int n = min(cnt[b], CAP);
    int chunk = (n + 7) >> 3;
    int beg = sub * chunk, end = min(n, beg + chunk);
    const int2* pb = pairs + (size_t)b * CAP;
    for (int i = beg + threadIdx.x; i < end; i += 256)
        atomicAdd(&indeg[pb[i].x], 1);
}

__global__ void k_dis(const int* indeg, float* dis) {
    int i = blockIdx.x * 256 + threadIdx.x;
    if (i < N_NODES) dis[i] = rsqrtf((float)indeg[i] + 1.0f);
}

// ---------- 3-kernel exclusive prefix scan of indeg -> offs ----------
__global__ __launch_bounds__(SCAN_B) void k_scan1(const int* indeg, int* incl, int* bsum) {
    __shared__ int tmp[SCAN_B];
    int i = blockIdx.x * SCAN_B + threadIdx.x;
    tmp[threadIdx.x] = (i < N_NODES) ? indeg[i] : 0;
    __syncthreads();
    for (int d = 1; d < SCAN_B; d <<= 1) {
        int t = (threadIdx.x >= d) ? tmp[threadIdx.x - d] : 0;
        __syncthreads();
        tmp[threadIdx.x] += t;
        __syncthreads();
    }
    if (i < N_NODES) incl[i] = tmp[threadIdx.x];
    if (threadIdx.x == SCAN_B - 1) bsum[blockIdx.x] = tmp[threadIdx.x];
}

__global__ void k_scan2(int* bsum) {
    __shared__ int tmp[128];
    tmp[threadIdx.x] = (threadIdx.x < NBLK) ? bsum[threadIdx.x] : 0;
    __syncthreads();
    for (int d = 1; d < 128; d <<= 1) {
        int t = (threadIdx.x >= d) ? tmp[threadIdx.x - d] : 0;
        __syncthreads();
        tmp[threadIdx.x] += t;
        __syncthreads();
    }
    if (threadIdx.x < NBLK) bsum[threadIdx.x] = tmp[threadIdx.x];
}

__global__ __launch_bounds__(SCAN_B) void k_scan3(const int* indeg, const int* incl,
                                                  const int* bsum, int* offs, int* fill) {
    int i = blockIdx.x * SCAN_B + threadIdx.x;
    if (i < N_NODES) {
        int pre = (blockIdx.x > 0) ? bsum[blockIdx.x - 1] : 0;
        offs[i] = incl[i] - indeg[i] + pre;
        fill[i] = 0;
    }
}

// ---------- phase 2: CSR placement from buckets (bucket-affine) ----------
__global__ __launch_bounds__(256) void k_place2(const int2* pairs, const int* cnt,
                                                const int* offs, int* fill, int* srcs) {
    int b = blockIdx.x & 63;
    int sub = blockIdx.x >> 6;
    int n = min(cnt[b], CAP);
    int chunk = (n + 7) >> 3;
    int beg = sub * chunk, end = min(n, beg + chunk);
    const int2* pb = pairs + (size_t)b * CAP;
    for (int i = beg + threadIdx.x; i < end; i += 256) {
        int2 v = pb[i];
        int p = offs[v.x] + atomicAdd(&fill[v.x], 1);
        srcs[p] = v.y;
    }
}

// ---------- projection via MFMA: g[i,:] = bf16( dis[i] * (h[i,:] @ W) ) ----------
template <int K, typename IT>
__global__ __launch_bounds__(256) void k_proj(const IT* __restrict__ in,
                                              const float* __restrict__ W,
                                              const float* __restrict__ dis,
                                              unsigned short* __restrict__ g) {
    const int NS = K / 32;
    int wave = threadIdx.x >> 6, lane = threadIdx.x & 63;
    int m = lane & 15, quad = lane >> 4;
    bf8_t Bf[NS][4];
#pragma unroll
    for (int s = 0; s < NS; s++)
#pragma unroll
        for (int t = 0; t < 4; t++)
#pragma unroll
            for (int j = 0; j < 8; j++)
                Bf[s][t][j] = f2bf(W[(s * 32 + quad * 8 + j) * 64 + t * 16 + m]);

    const int nchunks = N_NODES / 16;  // 6250
    const int stride = gridDim.x * 4;
    for (int chunk = blockIdx.x * 4 + wave; chunk < nchunks; chunk += stride) {
        int r0 = chunk * 16;
        const IT* src = in + (size_t)(r0 + m) * K + quad * 8;
        f4_t acc[4] = {{0.f, 0.f, 0.f, 0.f}, {0.f, 0.f, 0.f, 0.f},
                       {0.f, 0.f, 0.f, 0.f}, {0.f, 0.f, 0.f, 0.f}};
#pragma unroll
        for (int s = 0; s < NS; s++) {
            bf8_t a;
#pragma unroll
            for (int j = 0; j < 8; j++) a[j] = tobf(src[s * 32 + j]);
#pragma unroll
            for (int t = 0; t < 4; t++)
                acc[t] = __builtin_amdgcn_mfma_f32_16x16x32_bf16(a, Bf[s][t], acc[t], 0, 0, 0);
        }
        float dv[4];
#pragma unroll
        for (int i = 0; i < 4; i++) dv[i] = dis[r0 + quad * 4 + i];
#pragma unroll
        for (int t = 0; t < 4; t++)
#pragma unroll
            for (int i = 0; i < 4; i++)
                g[(size_t)(r0 + quad * 4 + i) * 64 + t * 16 + m] =
                    (unsigned short)f2bf(dv[i] * acc[t][i]);
    }
}

// ---------- CSR aggregation + finalize (bf16 in/out, fp32 accumulate, 8-deep MLP) ----------
template <bool RELU>
__global__ __launch_bounds__(256) void k_agg(const unsigned short* __restrict__ g,
                                             const int* __restrict__ srcs,
                                             const int* __restrict__ offs,
                                             const int* __restrict__ indeg,
                                             const float* __restrict__ dis,
                                             const float* __restrict__ b,
                                             unsigned short* __restrict__ out) {
    int node = (blockIdx.x * 256 + threadIdx.x) >> 6;
    int lane = threadIdx.x & 63;
    if (node >= N_NODES) return;
    int beg = offs[node];
    int deg = indeg[node];
    float a0 = bf2f(g[(size_t)node * 64 + lane]);  // self loop
    float a1 = 0.f, a2 = 0.f, a3 = 0.f, a4 = 0.f, a5 = 0.f, a6 = 0.f, a7 = 0.f;
    int d = 0;
    while (d < deg) {
        int cnt = min(deg - d, 64);
        int sv = (lane < cnt) ? srcs[beg + d + lane] : 0;
        int j = 0;
        for (; j + 8 <= cnt; j += 8) {
            int s0 = __shfl(sv, j),     s1 = __shfl(sv, j + 1);
            int s2 = __shfl(sv, j + 2), s3 = __shfl(sv, j + 3);
            int s4 = __shfl(sv, j + 4), s5 = __shfl(sv, j + 5);
            int s6 = __shfl(sv, j + 6), s7 = __shfl(sv, j + 7);
            a0 += bf2f(g[(size_t)s0 * 64 + lane]);
            a1 += bf2f(g[(size_t)s1 * 64 + lane]);
            a2 += bf2f(g[(size_t)s2 * 64 + lane]);
            a3 += bf2f(g[(size_t)s3 * 64 + lane]);
            a4 += bf2f(g[(size_t)s4 * 64 + lane]);
            a5 += bf2f(g[(size_t)s5 * 64 + lane]);
            a6 += bf2f(g[(size_t)s6 * 64 + lane]);
            a7 += bf2f(g[(size_t)s7 * 64 + lane]);
        }
        for (; j < cnt; j++) {
            int s = __shfl(sv, j);
            a0 += bf2f(g[(size_t)s * 64 + lane]);
        }
        d += cnt;
    }
    float v = dis[node] * (((a0 + a1) + (a2 + a3)) + ((a4 + a5) + (a6 + a7))) + b[lane];
    if (RELU) v = fmaxf(v, 0.f);
    out[(size_t)node * 64 + lane] = (unsigned short)f2bf(v);
}

// ---------- pooling (batch sorted, bf16 in): per-graph sums + counts ----------
__global__ void k_pool(const unsigned short* h, const int* bat, const int* flag,
                       float* sums, float* cnts) {
    const int R = 128;
    int wave = (blockIdx.x * 256 + threadIdx.x) >> 6;
    int lane = threadIdx.x & 63;
    int base = wave * R;
    if (base >= N_NODES) return;
    int f = *flag;
    int end = min(base + R, N_NODES);
    float acc = 0.f;
    int cur = ldidx(bat, f, (size_t)base);
    int cnt = 0;
    for (int r = base; r < end; r++) {
        int b = ldidx(bat, f, (size_t)r);
        if (b != cur) {
            if ((unsigned)cur < N_GRAPHS) {
                atomicAdd(&sums[cur * 64 + lane], acc);
                if (lane == 0) atomicAdd(&cnts[cur], (float)cnt);
            }
            acc = 0.f;
            cnt = 0;
            cur = b;
        }
        acc += bf2f(h[(size_t)r * 64 + lane]);
        cnt++;
    }
    if ((unsigned)cur < N_GRAPHS) {
        atomicAdd(&sums[cur * 64 + lane], acc);
        if (lane == 0) atomicAdd(&cnts[cur], (float)cnt);
    }
}

// ---------- head: out[g,o] = (sums[g,:]/cnt[g]) @ Wlin + blin (fp32 out) ----------
__global__ void k_head(const float* sums, const float* cnts, const float* Wlin,
                       const float* blin, float* out) {
    int t = blockIdx.x * 64 + threadIdx.x;
    if (t < N_GRAPHS * N_OUT) {
        int gph = t / N_OUT, o = t % N_OUT;
        float c = fmaxf(cnts[gph], 1.0f);
        float a = 0.f;
        for (int j = 0; j < HID; j++) a += sums[gph * 64 + j] * Wlin[j * N_OUT + o];
        out[t] = a / c + blin[o];
    }
}

extern "C" void kernel_launch(void* const* d_in, const int* in_sizes, int n_in,
                              void* d_out, int out_size, void* d_ws, size_t ws_size,
                              hipStream_t stream) {
    // --- resolve inputs by SIZE (robust to any harness input ordering) ---
    const float *x = nullptr, *W1 = nullptr, *W2 = nullptr, *W3 = nullptr, *Wlin = nullptr;
    const float *b1 = nullptr, *b2 = nullptr, *b3 = nullptr, *blin = nullptr;
    const int *ei = nullptr, *bat = nullptr;
    int n4096 = 0, n64 = 0;
    for (int i = 0; i < n_in; i++) {
        switch (in_sizes[i]) {
            case N_NODES * N_FEAT:  x    = (const float*)d_in[i]; break;
            case 2 * N_EDGES:       ei   = (const int*)d_in[i];   break;
            case N_NODES:           bat  = (const int*)d_in[i];   break;
            case N_FEAT * HID:      W1   = (const float*)d_in[i]; break;
            case HID * HID:
                if (n4096++ == 0) W2 = (const float*)d_in[i];
                else              W3 = (const float*)d_in[i];
                break;
            case HID * N_OUT:       Wlin = (const float*)d_in[i]; break;
            case HID:
                if (n64 == 0) b1 = (const float*)d_in[i];
                else if (n64 == 1) b2 = (const float*)d_in[i];
                else b3 = (const float*)d_in[i];
                n64++;
                break;
            case N_OUT:             blin = (const float*)d_in[i]; break;
            default: break;
        }
    }
    if (!x || !ei || !bat || !W1 || !W2 || !W3 || !Wlin || !b1 || !b2 || !b3 || !blin) {
        x    = (const float*)d_in[0];
        ei   = (const int*)d_in[1];
        bat  = (const int*)d_in[2];
        W1   = (const float*)d_in[3];  b1   = (const float*)d_in[4];
        W2   = (const float*)d_in[5];  b2   = (const float*)d_in[6];
        W3   = (const float*)d_in[7];  b3   = (const float*)d_in[8];
        Wlin = (const float*)d_in[9];  blin = (const float*)d_in[10];
    }
    float* out = (float*)d_out;  // fp32 output

    char* ws = (char*)d_ws;
    size_t off = 0;
    int2*           pairs = (int2*)(ws + off);           off += (size_t)NBUCK * CAP * 8;
    unsigned short* A     = (unsigned short*)(ws + off); off += (size_t)N_NODES * 64 * 2;
    unsigned short* G     = (unsigned short*)(ws + off); off += (size_t)N_NODES * 64 * 2;
    float*          dis   = (float*)(ws + off);          off += (size_t)N_NODES * 4;
    float*          sums  = (float*)(ws + off);          off += (size_t)N_GRAPHS * HID * 4;
    float*          cnts  = (float*)(ws + off);          off += (size_t)N_GRAPHS * 4;
    int*            indeg = (int*)(ws + off);            off += (size_t)N_NODES * 4;
    int*            bcnt  = (int*)(ws + off);            off += NBUCK * 4;   // adjacent to indeg
    int*            incl  = (int*)(ws + off);            off += (size_t)N_NODES * 4;
    int*            offs  = (int*)(ws + off);            off += (size_t)N_NODES * 4;
    int*            fill  = (int*)(ws + off);            off += (size_t)N_NODES * 4;
    int*            bsum  = (int*)(ws + off);            off += 128 * 4;
    int*            srcs  = (int*)(ws + off);            off += (size_t)N_EDGES * 4;
    int*            flag  = (int*)(ws + off);            off += 4;

    const int nb_nodes  = (N_NODES + 255) / 256;
    const int nb_agg    = (N_NODES * 64 + 255) / 256;
    const int nb_bucket = (N_EDGES + 2047) / 2048;  // 782

    // --- index dtype detection ---
    k_detect<<<1, 256, 0, stream>>>(ei, flag);

    // --- CSR build (bucketed two-phase; reused by all 3 convs) ---
    hipMemsetAsync(indeg, 0, (size_t)(N_NODES + NBUCK) * 4, stream);  // indeg + bcnt
    k_bucket<<<nb_bucket, 256, 0, stream>>>(ei, flag, pairs, bcnt);
    k_deg2<<<512, 256, 0, stream>>>(pairs, bcnt, indeg);
    k_dis<<<nb_nodes, 256, 0, stream>>>(indeg, dis);
    k_scan1<<<NBLK, SCAN_B, 0, stream>>>(indeg, incl, bsum);
    k_scan2<<<1, 128, 0, stream>>>(bsum);
    k_scan3<<<NBLK, SCAN_B, 0, stream>>>(indeg, incl, bsum, offs, fill);
    k_place2<<<512, 256, 0, stream>>>(pairs, bcnt, offs, fill, srcs);

    // conv1: x(fp32,128) -> G(bf16) -> A(bf16)
    k_proj<128, float><<<512, 256, 0, stream>>>(x, W1, dis, G);
    k_agg<true><<<nb_agg, 256, 0, stream>>>(G, srcs, offs, indeg, dis, b1, A);

    // conv2: A -> G -> A
    k_proj<64, unsigned short><<<512, 256, 0, stream>>>(A, W2, dis, G);
    k_agg<true><<<nb_agg, 256, 0, stream>>>(G, srcs, offs, indeg, dis, b2, A);

    // conv3: A -> G -> A (no relu)
    k_proj<64, unsigned short><<<512, 256, 0, stream>>>(A, W3, dis, G);
    k_agg<false><<<nb_agg, 256, 0, stream>>>(G, srcs, offs, indeg, dis, b3, A);

    // pool + head
    hipMemsetAsync(sums, 0, (size_t)(N_GRAPHS * HID + N_GRAPHS) * 4, stream);
    const int nwaves = (N_NODES + 127) / 128;
    k_pool<<<(nwaves * 64 + 255) / 256, 256, 0, stream>>>(A, bat, flag, sums, cnts);
    k_head<<<(N_GRAPHS * N_OUT + 63) / 64, 64, 0, stream>>>(sums, cnts, Wlin, blin, out);
}

// Round 11
// 490.391 us; speedup vs baseline: 1.0137x; 1.0137x over previous
//
#include <hip/hip_runtime.h>
#include <hip/hip_bf16.h>

#define N_NODES 100000
#define N_EDGES 1600000
#define N_FEAT 128
#define HID 64
#define N_GRAPHS 64
#define N_OUT 10
#define SCAN_B 1024
#define NBLK ((N_NODES + SCAN_B - 1) / SCAN_B)  // 98
#define NBUCK 64
#define RANGE64 ((N_NODES + NBUCK - 1) / NBUCK)  // 1563
#define CAP 40000                                 // mean 25000/bucket, >60 sigma headroom

typedef __attribute__((ext_vector_type(8))) short bf8_t;   // 8 bf16 in 4 VGPRs
typedef __attribute__((ext_vector_type(4))) float f4_t;    // MFMA accumulator

__device__ __forceinline__ short f2bf(float f) {
    __hip_bfloat16 h = __float2bfloat16(f);
    return *(short*)&h;
}
__device__ __forceinline__ float bf2f(unsigned short u) {
    unsigned v = ((unsigned)u) << 16;
    return __builtin_bit_cast(float, v);
}
__device__ __forceinline__ short tobf(float v) { return f2bf(v); }
__device__ __forceinline__ short tobf(unsigned short v) { return (short)v; }
// fp8 e4m3 (gfx950 native OCP format; encode+decode via same HW, self-consistent)
__device__ __forceinline__ unsigned char f2fp8(float v) {
    int p = __builtin_amdgcn_cvt_pk_fp8_f32(v, v, 0, false);
    return (unsigned char)(p & 0xFF);
}
__device__ __forceinline__ float fp82f(unsigned char b) {
    return __builtin_amdgcn_cvt_f32_fp8((int)b, 0);
}

// ---------- index dtype probe: 1 = int64 storage, 0 = int32 storage ----------
__global__ void k_detect(const int* raw, int* flag) {
    __shared__ int any;
    if (threadIdx.x == 0) any = 0;
    __syncthreads();
    int v = raw[2 * threadIdx.x + 1] | raw[2 * (threadIdx.x + 256) + 1] |
            raw[2 * (threadIdx.x + 512) + 1] | raw[2 * (threadIdx.x + 768) + 1];
    if (v != 0) any = 1;  // benign race
    __syncthreads();
    if (threadIdx.x == 0) *flag = (any == 0) ? 1 : 0;
}

__device__ __forceinline__ int ldidx(const int* raw, int f, size_t i) {
    return f ? raw[2 * i] : raw[i];
}

// ---------- phase 1: bin edges into 64 col-range buckets (LDS-aggregated cursors) ----------
__global__ __launch_bounds__(256) void k_bucket(const int* ei, const int* flag,
                                                int2* pairs, int* cnt) {
    __shared__ int lcnt[NBUCK];
    __shared__ int gbase[NBUCK];
    int f = *flag;
    if (threadIdx.x < NBUCK) lcnt[threadIdx.x] = 0;
    __syncthreads();
    int base = blockIdx.x * 2048;
    int r[8], lpos[8], c[8], s[8];
#pragma unroll
    for (int i = 0; i < 8; i++) {
        int e = base + i * 256 + threadIdx.x;
        r[i] = -1;
        if (e < N_EDGES) {
            c[i] = ldidx(ei, f, (size_t)N_EDGES + e);
            s[i] = ldidx(ei, f, (size_t)e);
            if ((unsigned)c[i] < N_NODES && (unsigned)s[i] < N_NODES) {
                r[i] = c[i] / RANGE64;
                lpos[i] = atomicAdd(&lcnt[r[i]], 1);
            }
        }
    }
    __syncthreads();
    if (threadIdx.x < NBUCK && lcnt[threadIdx.x] > 0)
        gbase[threadIdx.x] = atomicAdd(&cnt[threadIdx.x], lcnt[threadIdx.x]);
    __syncthreads();
#pragma unroll
    for (int i = 0; i < 8; i++) {
        if (r[i] >= 0) {
            int p = gbase[r[i]] + lpos[i];
            if (p < CAP) {
                int2 v; v.x = c[i]; v.y = s[i];
                pairs[(size_t)r[i] * CAP + p] = v;
            }
        }
    }
}

// ---------- in-degree from buckets (bucket-affine: blockIdx&63 = bucket) ----------
__global__ __launch_bounds__(256) void k_deg2(const int2* pairs, const int* cnt, int* indeg) {
    int b = blockIdx.x & 63;
    int sub = blockIdx.x >> 6;  // 0..7
    int n = min(cnt[b], CAP);
    int chunk = (n + 7) >> 3;
    int beg = sub * chunk, end = min(n, beg + chunk);
    const int2* pb = pairs + (size_t)b * CAP;
    for (int i = beg + threadIdx.x; i < end; i += 256)
        atomicAdd(&indeg[pb[i].x], 1);
}

__global__ void k_dis(const int* indeg, float* dis) {
    int i = blockIdx.x * 256 + threadIdx.x;
    if (i < N_NODES) dis[i] = rsqrtf((float)indeg[i] + 1.0f);
}

// ---------- 3-kernel exclusive prefix scan of indeg -> offs ----------
__global__ __launch_bounds__(SCAN_B) void k_scan1(const int* indeg, int* incl, int* bsum) {
    __shared__ int tmp[SCAN_B];
    int i = blockIdx.x * SCAN_B + threadIdx.x;
    tmp[threadIdx.x] = (i < N_NODES) ? indeg[i] : 0;
    __syncthreads();
    for (int d = 1; d < SCAN_B; d <<= 1) {
        int t = (threadIdx.x >= d) ? tmp[threadIdx.x - d] : 0;
        __syncthreads();
        tmp[threadIdx.x] += t;
        __syncthreads();
    }
    if (i < N_NODES) incl[i] = tmp[threadIdx.x];
    if (threadIdx.x == SCAN_B - 1) bsum[blockIdx.x] = tmp[threadIdx.x];
}

__global__ void k_scan2(int* bsum) {
    __shared__ int tmp[128];
    tmp[threadIdx.x] = (threadIdx.x < NBLK) ? bsum[threadIdx.x] : 0;
    __syncthreads();
    for (int d = 1; d < 128; d <<= 1) {
        int t = (threadIdx.x >= d) ? tmp[threadIdx.x - d] : 0;
        __syncthreads();
        tmp[threadIdx.x] += t;
        __syncthreads();
    }
    if (threadIdx.x < NBLK) bsum[threadIdx.x] = tmp[threadIdx.x];
}

__global__ __launch_bounds__(SCAN_B) void k_scan3(const int* indeg, const int* incl,
                                                  const int* bsum, int* offs, int* fill) {
    int i = blockIdx.x * SCAN_B + threadIdx.x;
    if (i < N_NODES) {
        int pre = (blockIdx.x > 0) ? bsum[blockIdx.x - 1] : 0;
        offs[i] = incl[i] - indeg[i] + pre;
        fill[i] = 0;
    }
}

// ---------- phase 2: CSR placement from buckets (bucket-affine) ----------
__global__ __launch_bounds__(256) void k_place2(const int2* pairs, const int* cnt,
                                                const int* offs, int* fill, int* srcs) {
    int b = blockIdx.x & 63;
    int sub = blockIdx.x >> 6;
    int n = min(cnt[b], CAP);
    int chunk = (n + 7) >> 3;
    int beg = sub * chunk, end = min(n, beg + chunk);
    const int2* pb = pairs + (size_t)b * CAP;
    for (int i = beg + threadIdx.x; i < end; i += 256) {
        int2 v = pb[i];
        int p = offs[v.x] + atomicAdd(&fill[v.x], 1);
        srcs[p] = v.y;
    }
}

// ---------- projection via MFMA: g[i,:] = fp8( dis[i] * (h[i,:] @ W) ) ----------
template <int K, typename IT>
__global__ __launch_bounds__(256) void k_proj(const IT* __restrict__ in,
                                              const float* __restrict__ W,
                                              const float* __restrict__ dis,
                                              unsigned char* __restrict__ g) {
    const int NS = K / 32;
    int wave = threadIdx.x >> 6, lane = threadIdx.x & 63;
    int m = lane & 15, quad = lane >> 4;
    bf8_t Bf[NS][4];
#pragma unroll
    for (int s = 0; s < NS; s++)
#pragma unroll
        for (int t = 0; t < 4; t++)
#pragma unroll
            for (int j = 0; j < 8; j++)
                Bf[s][t][j] = f2bf(W[(s * 32 + quad * 8 + j) * 64 + t * 16 + m]);

    const int nchunks = N_NODES / 16;  // 6250
    const int stride = gridDim.x * 4;
    for (int chunk = blockIdx.x * 4 + wave; chunk < nchunks; chunk += stride) {
        int r0 = chunk * 16;
        const IT* src = in + (size_t)(r0 + m) * K + quad * 8;
        f4_t acc[4] = {{0.f, 0.f, 0.f, 0.f}, {0.f, 0.f, 0.f, 0.f},
                       {0.f, 0.f, 0.f, 0.f}, {0.f, 0.f, 0.f, 0.f}};
#pragma unroll
        for (int s = 0; s < NS; s++) {
            bf8_t a;
#pragma unroll
            for (int j = 0; j < 8; j++) a[j] = tobf(src[s * 32 + j]);
#pragma unroll
            for (int t = 0; t < 4; t++)
                acc[t] = __builtin_amdgcn_mfma_f32_16x16x32_bf16(a, Bf[s][t], acc[t], 0, 0, 0);
        }
        float dv[4];
#pragma unroll
        for (int i = 0; i < 4; i++) dv[i] = dis[r0 + quad * 4 + i];
#pragma unroll
        for (int t = 0; t < 4; t++)
#pragma unroll
            for (int i = 0; i < 4; i++)
                g[(size_t)(r0 + quad * 4 + i) * 64 + t * 16 + m] = f2fp8(dv[i] * acc[t][i]);
    }
}

// ---------- CSR aggregation + finalize (fp8 gathers, fp32 accumulate, bf16 out) ----------
template <bool RELU>
__global__ __launch_bounds__(256) void k_agg(const unsigned char* __restrict__ g,
                                             const int* __restrict__ srcs,
                                             const int* __restrict__ offs,
                                             const int* __restrict__ indeg,
                                             const float* __restrict__ dis,
                                             const float* __restrict__ b,
                                             unsigned short* __restrict__ out) {
    int node = (blockIdx.x * 256 + threadIdx.x) >> 6;
    int lane = threadIdx.x & 63;
    if (node >= N_NODES) return;
    int beg = offs[node];
    int deg = indeg[node];
    float a0 = fp82f(g[(size_t)node * 64 + lane]);  // self loop
    float a1 = 0.f, a2 = 0.f, a3 = 0.f, a4 = 0.f, a5 = 0.f, a6 = 0.f, a7 = 0.f;
    int d = 0;
    while (d < deg) {
        int cnt = min(deg - d, 64);
        int sv = (lane < cnt) ? srcs[beg + d + lane] : 0;
        int j = 0;
        for (; j + 8 <= cnt; j += 8) {
            int s0 = __shfl(sv, j),     s1 = __shfl(sv, j + 1);
            int s2 = __shfl(sv, j + 2), s3 = __shfl(sv, j + 3);
            int s4 = __shfl(sv, j + 4), s5 = __shfl(sv, j + 5);
            int s6 = __shfl(sv, j + 6), s7 = __shfl(sv, j + 7);
            a0 += fp82f(g[(size_t)s0 * 64 + lane]);
            a1 += fp82f(g[(size_t)s1 * 64 + lane]);
            a2 += fp82f(g[(size_t)s2 * 64 + lane]);
            a3 += fp82f(g[(size_t)s3 * 64 + lane]);
            a4 += fp82f(g[(size_t)s4 * 64 + lane]);
            a5 += fp82f(g[(size_t)s5 * 64 + lane]);
            a6 += fp82f(g[(size_t)s6 * 64 + lane]);
            a7 += fp82f(g[(size_t)s7 * 64 + lane]);
        }
        for (; j < cnt; j++) {
            int s = __shfl(sv, j);
            a0 += fp82f(g[(size_t)s * 64 + lane]);
        }
        d += cnt;
    }
    float v = dis[node] * (((a0 + a1) + (a2 + a3)) + ((a4 + a5) + (a6 + a7))) + b[lane];
    if (RELU) v = fmaxf(v, 0.f);
    out[(size_t)node * 64 + lane] = (unsigned short)f2bf(v);
}

// ---------- pooling (batch sorted, bf16 in): per-graph sums + counts ----------
__global__ void k_pool(const unsigned short* h, const int* bat, const int* flag,
                       float* sums, float* cnts) {
    const int R = 128;
    int wave = (blockIdx.x * 256 + threadIdx.x) >> 6;
    int lane = threadIdx.x & 63;
    int base = wave * R;
    if (base >= N_NODES) return;
    int f = *flag;
    int end = min(base + R, N_NODES);
    float acc = 0.f;
    int cur = ldidx(bat, f, (size_t)base);
    int cnt = 0;
    for (int r = base; r < end; r++) {
        int b = ldidx(bat, f, (size_t)r);
        if (b != cur) {
            if ((unsigned)cur < N_GRAPHS) {
                atomicAdd(&sums[cur * 64 + lane], acc);
                if (lane == 0) atomicAdd(&cnts[cur], (float)cnt);
            }
            acc = 0.f;
            cnt = 0;
            cur = b;
        }
        acc += bf2f(h[(size_t)r * 64 + lane]);
        cnt++;
    }
    if ((unsigned)cur < N_GRAPHS) {
        atomicAdd(&sums[cur * 64 + lane], acc);
        if (lane == 0) atomicAdd(&cnts[cur], (float)cnt);
    }
}

// ---------- head: out[g,o] = (sums[g,:]/cnt[g]) @ Wlin + blin (fp32 out) ----------
__global__ void k_head(const float* sums, const float* cnts, const float* Wlin,
                       const float* blin, float* out) {
    int t = blockIdx.x * 64 + threadIdx.x;
    if (t < N_GRAPHS * N_OUT) {
        int gph = t / N_OUT, o = t % N_OUT;
        float c = fmaxf(cnts[gph], 1.0f);
        float a = 0.f;
        for (int j = 0; j < HID; j++) a += sums[gph * 64 + j] * Wlin[j * N_OUT + o];
        out[t] = a / c + blin[o];
    }
}

extern "C" void kernel_launch(void* const* d_in, const int* in_sizes, int n_in,
                              void* d_out, int out_size, void* d_ws, size_t ws_size,
                              hipStream_t stream) {
    // --- resolve inputs by SIZE (robust to any harness input ordering) ---
    const float *x = nullptr, *W1 = nullptr, *W2 = nullptr, *W3 = nullptr, *Wlin = nullptr;
    const float *b1 = nullptr, *b2 = nullptr, *b3 = nullptr, *blin = nullptr;
    const int *ei = nullptr, *bat = nullptr;
    int n4096 = 0, n64 = 0;
    for (int i = 0; i < n_in; i++) {
        switch (in_sizes[i]) {
            case N_NODES * N_FEAT:  x    = (const float*)d_in[i]; break;
            case 2 * N_EDGES:       ei   = (const int*)d_in[i];   break;
            case N_NODES:           bat  = (const int*)d_in[i];   break;
            case N_FEAT * HID:      W1   = (const float*)d_in[i]; break;
            case HID * HID:
                if (n4096++ == 0) W2 = (const float*)d_in[i];
                else              W3 = (const float*)d_in[i];
                break;
            case HID * N_OUT:       Wlin = (const float*)d_in[i]; break;
            case HID:
                if (n64 == 0) b1 = (const float*)d_in[i];
                else if (n64 == 1) b2 = (const float*)d_in[i];
                else b3 = (const float*)d_in[i];
                n64++;
                break;
            case N_OUT:             blin = (const float*)d_in[i]; break;
            default: break;
        }
    }
    if (!x || !ei || !bat || !W1 || !W2 || !W3 || !Wlin || !b1 || !b2 || !b3 || !blin) {
        x    = (const float*)d_in[0];
        ei   = (const int*)d_in[1];
        bat  = (const int*)d_in[2];
        W1   = (const float*)d_in[3];  b1   = (const float*)d_in[4];
        W2   = (const float*)d_in[5];  b2   = (const float*)d_in[6];
        W3   = (const float*)d_in[7];  b3   = (const float*)d_in[8];
        Wlin = (const float*)d_in[9];  blin = (const float*)d_in[10];
    }
    float* out = (float*)d_out;  // fp32 output

    char* ws = (char*)d_ws;
    size_t off = 0;
    int2*           pairs = (int2*)(ws + off);           off += (size_t)NBUCK * CAP * 8;
    unsigned short* A     = (unsigned short*)(ws + off); off += (size_t)N_NODES * 64 * 2;
    unsigned char*  G     = (unsigned char*)(ws + off);  off += (size_t)N_NODES * 64;
    float*          dis   = (float*)(ws + off);          off += (size_t)N_NODES * 4;
    float*          sums  = (float*)(ws + off);          off += (size_t)N_GRAPHS * HID * 4;
    float*          cnts  = (float*)(ws + off);          off += (size_t)N_GRAPHS * 4;
    int*            indeg = (int*)(ws + off);            off += (size_t)N_NODES * 4;
    int*            bcnt  = (int*)(ws + off);            off += NBUCK * 4;   // adjacent to indeg
    int*            incl  = (int*)(ws + off);            off += (size_t)N_NODES * 4;
    int*            offs  = (int*)(ws + off);            off += (size_t)N_NODES * 4;
    int*            fill  = (int*)(ws + off);            off += (size_t)N_NODES * 4;
    int*            bsum  = (int*)(ws + off);            off += 128 * 4;
    int*            srcs  = (int*)(ws + off);            off += (size_t)N_EDGES * 4;
    int*            flag  = (int*)(ws + off);            off += 4;

    const int nb_nodes  = (N_NODES + 255) / 256;
    const int nb_agg    = (N_NODES * 64 + 255) / 256;
    const int nb_bucket = (N_EDGES + 2047) / 2048;  // 782

    // --- index dtype detection ---
    k_detect<<<1, 256, 0, stream>>>(ei, flag);

    // --- CSR build (bucketed two-phase; reused by all 3 convs) ---
    hipMemsetAsync(indeg, 0, (size_t)(N_NODES + NBUCK) * 4, stream);  // indeg + bcnt
    k_bucket<<<nb_bucket, 256, 0, stream>>>(ei, flag, pairs, bcnt);
    k_deg2<<<512, 256, 0, stream>>>(pairs, bcnt, indeg);
    k_dis<<<nb_nodes, 256, 0, stream>>>(indeg, dis);
    k_scan1<<<NBLK, SCAN_B, 0, stream>>>(indeg, incl, bsum);
    k_scan2<<<1, 128, 0, stream>>>(bsum);
    k_scan3<<<NBLK, SCAN_B, 0, stream>>>(indeg, incl, bsum, offs, fill);
    k_place2<<<512, 256, 0, stream>>>(pairs, bcnt, offs, fill, srcs);

    // conv1: x(fp32,128) -> G(fp8) -> A(bf16)
    k_proj<128, float><<<512, 256, 0, stream>>>(x, W1, dis, G);
    k_agg<true><<<nb_agg, 256, 0, stream>>>(G, srcs, offs, indeg, dis, b1, A);

    // conv2: A -> G -> A
    k_proj<64, unsigned short><<<512, 256, 0, stream>>>(A, W2, dis, G);
    k_agg<true><<<nb_agg, 256, 0, stream>>>(G, srcs, offs, indeg, dis, b2, A);

    // conv3: A -> G -> A (no relu)
    k_proj<64, unsigned short><<<512, 256, 0, stream>>>(A, W3, dis, G);
    k_agg<false><<<nb_agg, 256, 0, stream>>>(G, srcs, offs, indeg, dis, b3, A);

    // pool + head
    hipMemsetAsync(sums, 0, (size_t)(N_GRAPHS * HID + N_GRAPHS) * 4, stream);
    const int nwaves = (N_NODES + 127) / 128;
    k_pool<<<(nwaves * 64 + 255) / 256, 256, 0, stream>>>(A, bat, flag, sums, cnts);
    k_head<<<(N_GRAPHS * N_OUT + 63) / 64, 64, 0, stream>>>(sums, cnts, Wlin, blin, out);
}

// Round 13
// 459.992 us; speedup vs baseline: 1.0807x; 1.0661x over previous
//
#include <hip/hip_runtime.h>
#include <hip/hip_bf16.h>

#define N_NODES 100000
#define N_EDGES 1600000
#define N_FEAT 128
#define HID 64
#define N_GRAPHS 64
#define N_OUT 10
#define SCAN_B 1024
#define NBLK ((N_NODES + SCAN_B - 1) / SCAN_B)  // 98
#define NBUCK 64
#define RANGE64 ((N_NODES + NBUCK - 1) / NBUCK)  // 1563
#define CAP 40000
#define SRCS_CAP (N_EDGES + 8 * N_NODES)  // padded CSR upper bound

typedef __attribute__((ext_vector_type(8))) short bf8_t;   // 8 bf16 in 4 VGPRs
typedef __attribute__((ext_vector_type(4))) float f4_t;    // MFMA accumulator
typedef __attribute__((ext_vector_type(2))) float f2_t;

__device__ __forceinline__ short f2bf(float f) {
    __hip_bfloat16 h = __float2bfloat16(f);
    return *(short*)&h;
}
__device__ __forceinline__ float bf2f(unsigned short u) {
    unsigned v = ((unsigned)u) << 16;
    return __builtin_bit_cast(float, v);
}
__device__ __forceinline__ short tobf(float v) { return f2bf(v); }
__device__ __forceinline__ short tobf(unsigned short v) { return (short)v; }
__device__ __forceinline__ unsigned char f2fp8(float v) {
    int p = __builtin_amdgcn_cvt_pk_fp8_f32(v, v, 0, false);
    return (unsigned char)(p & 0xFF);
}
// decode 4 fp8 bytes (one dword) into acc[base..base+3] via 2 pk-converts
__device__ __forceinline__ void fp8acc4(float* acc, unsigned w) {
    f2_t lo = __builtin_amdgcn_cvt_pk_f32_fp8((int)w, false);
    f2_t hi = __builtin_amdgcn_cvt_pk_f32_fp8((int)w, true);
    acc[0] += lo[0]; acc[1] += lo[1]; acc[2] += hi[0]; acc[3] += hi[1];
}

// ---------- index dtype probe ----------
__global__ void k_detect(const int* raw, int* flag) {
    __shared__ int any;
    if (threadIdx.x == 0) any = 0;
    __syncthreads();
    int v = raw[2 * threadIdx.x + 1] | raw[2 * (threadIdx.x + 256) + 1] |
            raw[2 * (threadIdx.x + 512) + 1] | raw[2 * (threadIdx.x + 768) + 1];
    if (v != 0) any = 1;
    __syncthreads();
    if (threadIdx.x == 0) *flag = (any == 0) ? 1 : 0;
}

__device__ __forceinline__ int ldidx(const int* raw, int f, size_t i) {
    return f ? raw[2 * i] : raw[i];
}

// ---------- phase 1: bin edges into 64 col-range buckets ----------
__global__ __launch_bounds__(256) void k_bucket(const int* ei, const int* flag,
                                                int2* pairs, int* cnt) {
    __shared__ int lcnt[NBUCK];
    __shared__ int gbase[NBUCK];
    int f = *flag;
    if (threadIdx.x < NBUCK) lcnt[threadIdx.x] = 0;
    __syncthreads();
    int base = blockIdx.x * 2048;
    int r[8], lpos[8], c[8], s[8];
#pragma unroll
    for (int i = 0; i < 8; i++) {
        int e = base + i * 256 + threadIdx.x;
        r[i] = -1;
        if (e < N_EDGES) {
            c[i] = ldidx(ei, f, (size_t)N_EDGES + e);
            s[i] = ldidx(ei, f, (size_t)e);
            if ((unsigned)c[i] < N_NODES && (unsigned)s[i] < N_NODES) {
                r[i] = c[i] / RANGE64;
                lpos[i] = atomicAdd(&lcnt[r[i]], 1);
            }
        }
    }
    __syncthreads();
    if (threadIdx.x < NBUCK && lcnt[threadIdx.x] > 0)
        gbase[threadIdx.x] = atomicAdd(&cnt[threadIdx.x], lcnt[threadIdx.x]);
    __syncthreads();
#pragma unroll
    for (int i = 0; i < 8; i++) {
        if (r[i] >= 0) {
            int p = gbase[r[i]] + lpos[i];
            if (p < CAP) {
                int2 v; v.x = c[i]; v.y = s[i];
                pairs[(size_t)r[i] * CAP + p] = v;
            }
        }
    }
}

// ---------- in-degree from buckets (bucket-affine) ----------
__global__ __launch_bounds__(256) void k_deg2(const int2* pairs, const int* cnt, int* indeg) {
    int b = blockIdx.x & 63;
    int sub = blockIdx.x >> 6;
    int n = min(cnt[b], CAP);
    int chunk = (n + 7) >> 3;
    int beg = sub * chunk, end = min(n, beg + chunk);
    const int2* pb = pairs + (size_t)b * CAP;
    for (int i = beg + threadIdx.x; i < end; i += 256)
        atomicAdd(&indeg[pb[i].x], 1);
}

__global__ void k_dis(const int* indeg, float* dis) {
    int i = blockIdx.x * 256 + threadIdx.x;
    if (i < N_NODES) dis[i] = rsqrtf((float)indeg[i] + 1.0f);
}

// ---------- prefix scan over PADDED degrees ((deg+7)&~7) ----------
__global__ __launch_bounds__(SCAN_B) void k_scan1(const int* indeg, int* incl, int* bsum) {
    __shared__ int tmp[SCAN_B];
    int i = blockIdx.x * SCAN_B + threadIdx.x;
    tmp[threadIdx.x] = (i < N_NODES) ? ((indeg[i] + 7) & ~7) : 0;
    __syncthreads();
    for (int d = 1; d < SCAN_B; d <<= 1) {
        int t = (threadIdx.x >= d) ? tmp[threadIdx.x - d] : 0;
        __syncthreads();
        tmp[threadIdx.x] += t;
        __syncthreads();
    }
    if (i < N_NODES) incl[i] = tmp[threadIdx.x];
    if (threadIdx.x == SCAN_B - 1) bsum[blockIdx.x] = tmp[threadIdx.x];
}

__global__ void k_scan2(int* bsum) {
    __shared__ int tmp[128];
    tmp[threadIdx.x] = (threadIdx.x < NBLK) ? bsum[threadIdx.x] : 0;
    __syncthreads();
    for (int d = 1; d < 128; d <<= 1) {
        int t = (threadIdx.x >= d) ? tmp[threadIdx.x - d] : 0;
        __syncthreads();
        tmp[threadIdx.x] += t;
        __syncthreads();
    }
    if (threadIdx.x < NBLK) bsum[threadIdx.x] = tmp[threadIdx.x];
}

__global__ __launch_bounds__(SCAN_B) void k_scan3(const int* indeg, const int* incl,
                                                  const int* bsum, int* offs, int* fill) {
    int i = blockIdx.x * SCAN_B + threadIdx.x;
    if (i < N_NODES) {
        int pre = (blockIdx.x > 0) ? bsum[blockIdx.x - 1] : 0;
        offs[i] = incl[i] - ((indeg[i] + 7) & ~7) + pre;
        fill[i] = 0;
    }
}

// ---------- phase 2: CSR placement from buckets (bucket-affine) ----------
__global__ __launch_bounds__(256) void k_place2(const int2* pairs, const int* cnt,
                                                const int* offs, int* fill, int* srcs) {
    int b = blockIdx.x & 63;
    int sub = blockIdx.x >> 6;
    int n = min(cnt[b], CAP);
    int chunk = (n + 7) >> 3;
    int beg = sub * chunk, end = min(n, beg + chunk);
    const int2* pb = pairs + (size_t)b * CAP;
    for (int i = beg + threadIdx.x; i < end; i += 256) {
        int2 v = pb[i];
        int p = offs[v.x] + atomicAdd(&fill[v.x], 1);
        srcs[p] = v.y;
    }
}

// ---------- pad slots [deg, pdeg) with the zero-row index ----------
__global__ void k_pad(const int* indeg, const int* offs, int* srcs) {
    int i = blockIdx.x * 256 + threadIdx.x;
    if (i < N_NODES) {
        int deg = indeg[i], pdeg = (deg + 7) & ~7, o = offs[i];
        for (int k = deg; k < pdeg; k++) srcs[o + k] = N_NODES;
    }
}

// ---------- projection via MFMA: g[i,:] = fp8( dis[i] * (h[i,:] @ W) ) ----------
template <int K, typename IT>
__global__ __launch_bounds__(256) void k_proj(const IT* __restrict__ in,
                                              const float* __restrict__ W,
                                              const float* __restrict__ dis,
                                              unsigned char* __restrict__ g) {
    // zero the pad row (row N_NODES, 64 B)
    if (blockIdx.x == 0 && threadIdx.x < 16)
        ((unsigned*)g)[N_NODES * 16 + threadIdx.x] = 0u;
    const int NS = K / 32;
    int wave = threadIdx.x >> 6, lane = threadIdx.x & 63;
    int m = lane & 15, quad = lane >> 4;
    bf8_t Bf[NS][4];
#pragma unroll
    for (int s = 0; s < NS; s++)
#pragma unroll
        for (int t = 0; t < 4; t++)
#pragma unroll
            for (int j = 0; j < 8; j++)
                Bf[s][t][j] = f2bf(W[(s * 32 + quad * 8 + j) * 64 + t * 16 + m]);

    const int nchunks = N_NODES / 16;  // 6250
    const int stride = gridDim.x * 4;
    for (int chunk = blockIdx.x * 4 + wave; chunk < nchunks; chunk += stride) {
        int r0 = chunk * 16;
        const IT* src = in + (size_t)(r0 + m) * K + quad * 8;
        f4_t acc[4] = {{0.f, 0.f, 0.f, 0.f}, {0.f, 0.f, 0.f, 0.f},
                       {0.f, 0.f, 0.f, 0.f}, {0.f, 0.f, 0.f, 0.f}};
#pragma unroll
        for (int s = 0; s < NS; s++) {
            bf8_t a;
#pragma unroll
            for (int j = 0; j < 8; j++) a[j] = tobf(src[s * 32 + j]);
#pragma unroll
            for (int t = 0; t < 4; t++)
                acc[t] = __builtin_amdgcn_mfma_f32_16x16x32_bf16(a, Bf[s][t], acc[t], 0, 0, 0);
        }
        float dv[4];
#pragma unroll
        for (int i = 0; i < 4; i++) dv[i] = dis[r0 + quad * 4 + i];
#pragma unroll
        for (int t = 0; t < 4; t++)
#pragma unroll
            for (int i = 0; i < 4; i++)
                g[(size_t)(r0 + quad * 4 + i) * 64 + t * 16 + m] = f2fp8(dv[i] * acc[t][i]);
    }
}

// ---------- CSR aggregation: 8 edges per VMEM instruction ----------
// lane = eg*8 + fg: lane gathers uint2 (8 fp8 feats, octet fg) of edge slot eg.
// acc[8] per lane; butterfly xor-reduce over eg (masks 8/16/32); lanes 0..7
// finalize+store the 128B bf16 row.
template <bool RELU>
__global__ __launch_bounds__(256) void k_agg(const unsigned char* __restrict__ g,
                                             const int* __restrict__ srcs,
                                             const int* __restrict__ offs,
                                             const int* __restrict__ indeg,
                                             const float* __restrict__ dis,
                                             const float* __restrict__ b,
                                             unsigned short* __restrict__ out) {
    int node = (blockIdx.x * 256 + threadIdx.x) >> 6;
    int lane = threadIdx.x & 63;
    if (node >= N_NODES) return;
    int eg = lane >> 3, fg = lane & 7;
    int beg = offs[node];
    int deg = indeg[node];
    int pdeg = (deg + 7) & ~7;
    float acc[8] = {0.f, 0.f, 0.f, 0.f, 0.f, 0.f, 0.f, 0.f};
    // self loop (count once: only eg==0 lanes)
    if (eg == 0) {
        uint2 w = *(const uint2*)(g + (size_t)node * 64 + fg * 8);
        fp8acc4(acc, w.x);
        fp8acc4(acc + 4, w.y);
    }
    int d = 0;
    while (d < pdeg) {
        int cnt = min(pdeg - d, 64);  // multiple of 8
        int sv = (lane < cnt) ? srcs[beg + d + lane] : (int)N_NODES;
        for (int k = 0; k < cnt; k += 8) {
            int s = __shfl(sv, k + eg);
            uint2 w = *(const uint2*)(g + (size_t)s * 64 + fg * 8);
            fp8acc4(acc, w.x);
            fp8acc4(acc + 4, w.y);
        }
        d += cnt;
    }
    // reduce across the 8 edge slots (lanes with same fg)
#pragma unroll
    for (int msk = 8; msk <= 32; msk <<= 1)
#pragma unroll
        for (int j = 0; j < 8; j++) acc[j] += __shfl_xor(acc[j], msk);
    if (lane < 8) {
        float dv = dis[node];
        unsigned o[4];
#pragma unroll
        for (int p = 0; p < 4; p++) {
            float v0 = dv * acc[2 * p]     + b[lane * 8 + 2 * p];
            float v1 = dv * acc[2 * p + 1] + b[lane * 8 + 2 * p + 1];
            if (RELU) { v0 = fmaxf(v0, 0.f); v1 = fmaxf(v1, 0.f); }
            o[p] = ((unsigned)(unsigned short)f2bf(v1) << 16) | (unsigned short)f2bf(v0);
        }
        *(uint4*)((char*)out + (size_t)node * 128 + lane * 16) =
            make_uint4(o[0], o[1], o[2], o[3]);
    }
}

// ---------- pooling (batch sorted, bf16 in) ----------
__global__ void k_pool(const unsigned short* h, const int* bat, const int* flag,
                       float* sums, float* cnts) {
    const int R = 128;
    int wave = (blockIdx.x * 256 + threadIdx.x) >> 6;
    int lane = threadIdx.x & 63;
    int base = wave * R;
    if (base >= N_NODES) return;
    int f = *flag;
    int end = min(base + R, N_NODES);
    float acc = 0.f;
    int cur = ldidx(bat, f, (size_t)base);
    int cnt = 0;
    for (int r = base; r < end; r++) {
        int b = ldidx(bat, f, (size_t)r);
        if (b != cur) {
            if ((unsigned)cur < N_GRAPHS) {
                atomicAdd(&sums[cur * 64 + lane], acc);
                if (lane == 0) atomicAdd(&cnts[cur], (float)cnt);
            }
            acc = 0.f;
            cnt = 0;
            cur = b;
        }
        acc += bf2f(h[(size_t)r * 64 + lane]);
        cnt++;
    }
    if ((unsigned)cur < N_GRAPHS) {
        atomicAdd(&sums[cur * 64 + lane], acc);
        if (lane == 0) atomicAdd(&cnts[cur], (float)cnt);
    }
}

// ---------- head ----------
__global__ void k_head(const float* sums, const float* cnts, const float* Wlin,
                       const float* blin, float* out) {
    int t = blockIdx.x * 64 + threadIdx.x;
    if (t < N_GRAPHS * N_OUT) {
        int gph = t / N_OUT, o = t % N_OUT;
        float c = fmaxf(cnts[gph], 1.0f);
        float a = 0.f;
        for (int j = 0; j < HID; j++) a += sums[gph * 64 + j] * Wlin[j * N_OUT + o];
        out[t] = a / c + blin[o];
    }
}

extern "C" void kernel_launch(void* const* d_in, const int* in_sizes, int n_in,
                              void* d_out, int out_size, void* d_ws, size_t ws_size,
                              hipStream_t stream) {
    const float *x = nullptr, *W1 = nullptr, *W2 = nullptr, *W3 = nullptr, *Wlin = nullptr;
    const float *b1 = nullptr, *b2 = nullptr, *b3 = nullptr, *blin = nullptr;
    const int *ei = nullptr, *bat = nullptr;
    int n4096 = 0, n64 = 0;
    for (int i = 0; i < n_in; i++) {
        switch (in_sizes[i]) {
            case N_NODES * N_FEAT:  x    = (const float*)d_in[i]; break;
            case 2 * N_EDGES:       ei   = (const int*)d_in[i];   break;
            case N_NODES:           bat  = (const int*)d_in[i];   break;
            case N_FEAT * HID:      W1   = (const float*)d_in[i]; break;
            case HID * HID:
                if (n4096++ == 0) W2 = (const float*)d_in[i];
                else              W3 = (const float*)d_in[i];
                break;
            case HID * N_OUT:       Wlin = (const float*)d_in[i]; break;
            case HID:
                if (n64 == 0) b1 = (const float*)d_in[i];
                else if (n64 == 1) b2 = (const float*)d_in[i];
                else b3 = (const float*)d_in[i];
                n64++;
                break;
            case N_OUT:             blin = (const float*)d_in[i]; break;
            default: break;
        }
    }
    if (!x || !ei || !bat || !W1 || !W2 || !W3 || !Wlin || !b1 || !b2 || !b3 || !blin) {
        x    = (const float*)d_in[0];
        ei   = (const int*)d_in[1];
        bat  = (const int*)d_in[2];
        W1   = (const float*)d_in[3];  b1   = (const float*)d_in[4];
        W2   = (const float*)d_in[5];  b2   = (const float*)d_in[6];
        W3   = (const float*)d_in[7];  b3   = (const float*)d_in[8];
        Wlin = (const float*)d_in[9];  blin = (const float*)d_in[10];
    }
    float* out = (float*)d_out;  // fp32 output

    char* ws = (char*)d_ws;
    size_t off = 0;
    int2*           pairs = (int2*)(ws + off);           off += (size_t)NBUCK * CAP * 8;
    unsigned short* A     = (unsigned short*)(ws + off); off += (size_t)N_NODES * 64 * 2;
    unsigned char*  G     = (unsigned char*)(ws + off);  off += (size_t)(N_NODES + 1) * 64;
    float*          dis   = (float*)(ws + off);          off += (size_t)N_NODES * 4;
    float*          sums  = (float*)(ws + off);          off += (size_t)N_GRAPHS * HID * 4;
    float*          cnts  = (float*)(ws + off);          off += (size_t)N_GRAPHS * 4;
    int*            indeg = (int*)(ws + off);            off += (size_t)N_NODES * 4;
    int*            bcnt  = (int*)(ws + off);            off += NBUCK * 4;   // adjacent to indeg
    int*            incl  = (int*)(ws + off);            off += (size_t)N_NODES * 4;
    int*            offs  = (int*)(ws + off);            off += (size_t)N_NODES * 4;
    int*            fill  = (int*)(ws + off);            off += (size_t)N_NODES * 4;
    int*            bsum  = (int*)(ws + off);            off += 128 * 4;
    int*            srcs  = (int*)(ws + off);            off += (size_t)SRCS_CAP * 4;
    int*            flag  = (int*)(ws + off);            off += 4;

    const int nb_nodes  = (N_NODES + 255) / 256;
    const int nb_agg    = (N_NODES * 64 + 255) / 256;
    const int nb_bucket = (N_EDGES + 2047) / 2048;  // 782

    k_detect<<<1, 256, 0, stream>>>(ei, flag);

    // --- CSR build (bucketed two-phase, degree-padded to x8) ---
    hipMemsetAsync(indeg, 0, (size_t)(N_NODES + NBUCK) * 4, stream);  // indeg + bcnt
    k_bucket<<<nb_bucket, 256, 0, stream>>>(ei, flag, pairs, bcnt);
    k_deg2<<<512, 256, 0, stream>>>(pairs, bcnt, indeg);
    k_dis<<<nb_nodes, 256, 0, stream>>>(indeg, dis);
    k_scan1<<<NBLK, SCAN_B, 0, stream>>>(indeg, incl, bsum);
    k_scan2<<<1, 128, 0, stream>>>(bsum);
    k_scan3<<<NBLK, SCAN_B, 0, stream>>>(indeg, incl, bsum, offs, fill);
    k_place2<<<512, 256, 0, stream>>>(pairs, bcnt, offs, fill, srcs);
    k_pad<<<nb_nodes, 256, 0, stream>>>(indeg, offs, srcs);

    // conv1: x(fp32,128) -> G(fp8) -> A(bf16)
    k_proj<128, float><<<512, 256, 0, stream>>>(x, W1, dis, G);
    k_agg<true><<<nb_agg, 256, 0, stream>>>(G, srcs, offs, indeg, dis, b1, A);

    // conv2: A -> G -> A
    k_proj<64, unsigned short><<<512, 256, 0, stream>>>(A, W2, dis, G);
    k_agg<true><<<nb_agg, 256, 0, stream>>>(G, srcs, offs, indeg, dis, b2, A);

    // conv3: A -> G -> A (no relu)
    k_proj<64, unsigned short><<<512, 256, 0, stream>>>(A, W3, dis, G);
    k_agg<false><<<nb_agg, 256, 0, stream>>>(G, srcs, offs, indeg, dis, b3, A);

    // pool + head
    hipMemsetAsync(sums, 0, (size_t)(N_GRAPHS * HID + N_GRAPHS) * 4, stream);
    const int nwaves = (N_NODES + 127) / 128;
    k_pool<<<(nwaves * 64 + 255) / 256, 256, 0, stream>>>(A, bat, flag, sums, cnts);
    k_head<<<(N_GRAPHS * N_OUT + 63) / 64, 64, 0, stream>>>(sums, cnts, Wlin, blin, out);
}

// Round 14
// 385.725 us; speedup vs baseline: 1.2888x; 1.1925x over previous
//
#include <hip/hip_runtime.h>
#include <hip/hip_bf16.h>

#define N_NODES 100000
#define N_EDGES 1600000
#define N_FEAT 128
#define HID 64
#define N_GRAPHS 64
#define N_OUT 10
#define SCAN_B 1024
#define NBLK ((N_NODES + SCAN_B - 1) / SCAN_B)  // 98
#define NBUCK 64
#define RANGE64 ((N_NODES + NBUCK - 1) / NBUCK)  // 1563
#define CAP 40000
#define SRCS_CAP (N_EDGES + 8 * N_NODES)  // padded CSR upper bound

typedef __attribute__((ext_vector_type(8))) short bf8_t;   // 8 bf16 in 4 VGPRs
typedef __attribute__((ext_vector_type(4))) float f4_t;    // MFMA accumulator
typedef __attribute__((ext_vector_type(2))) float f2_t;

__device__ __forceinline__ short f2bf(float f) {
    __hip_bfloat16 h = __float2bfloat16(f);
    return *(short*)&h;
}
__device__ __forceinline__ float bf2f(unsigned short u) {
    unsigned v = ((unsigned)u) << 16;
    return __builtin_bit_cast(float, v);
}
__device__ __forceinline__ short tobf(float v) { return f2bf(v); }
__device__ __forceinline__ short tobf(unsigned short v) { return (short)v; }
__device__ __forceinline__ unsigned char f2fp8(float v) {
    int p = __builtin_amdgcn_cvt_pk_fp8_f32(v, v, 0, false);
    return (unsigned char)(p & 0xFF);
}
// decode 4 fp8 bytes (one dword) into acc[0..3] via 2 pk-converts
__device__ __forceinline__ void fp8acc4(float* acc, unsigned w) {
    f2_t lo = __builtin_amdgcn_cvt_pk_f32_fp8((int)w, false);
    f2_t hi = __builtin_amdgcn_cvt_pk_f32_fp8((int)w, true);
    acc[0] += lo[0]; acc[1] += lo[1]; acc[2] += hi[0]; acc[3] += hi[1];
}

// ---------- index dtype probe ----------
__global__ void k_detect(const int* raw, int* flag) {
    __shared__ int any;
    if (threadIdx.x == 0) any = 0;
    __syncthreads();
    int v = raw[2 * threadIdx.x + 1] | raw[2 * (threadIdx.x + 256) + 1] |
            raw[2 * (threadIdx.x + 512) + 1] | raw[2 * (threadIdx.x + 768) + 1];
    if (v != 0) any = 1;
    __syncthreads();
    if (threadIdx.x == 0) *flag = (any == 0) ? 1 : 0;
}

__device__ __forceinline__ int ldidx(const int* raw, int f, size_t i) {
    return f ? raw[2 * i] : raw[i];
}

// ---------- phase 1: bin edges into 64 col-range buckets ----------
__global__ __launch_bounds__(256) void k_bucket(const int* ei, const int* flag,
                                                int2* pairs, int* cnt) {
    __shared__ int lcnt[NBUCK];
    __shared__ int gbase[NBUCK];
    int f = *flag;
    if (threadIdx.x < NBUCK) lcnt[threadIdx.x] = 0;
    __syncthreads();
    int base = blockIdx.x * 2048;
    int r[8], lpos[8], c[8], s[8];
#pragma unroll
    for (int i = 0; i < 8; i++) {
        int e = base + i * 256 + threadIdx.x;
        r[i] = -1;
        if (e < N_EDGES) {
            c[i] = ldidx(ei, f, (size_t)N_EDGES + e);
            s[i] = ldidx(ei, f, (size_t)e);
            if ((unsigned)c[i] < N_NODES && (unsigned)s[i] < N_NODES) {
                r[i] = c[i] / RANGE64;
                lpos[i] = atomicAdd(&lcnt[r[i]], 1);
            }
        }
    }
    __syncthreads();
    if (threadIdx.x < NBUCK && lcnt[threadIdx.x] > 0)
        gbase[threadIdx.x] = atomicAdd(&cnt[threadIdx.x], lcnt[threadIdx.x]);
    __syncthreads();
#pragma unroll
    for (int i = 0; i < 8; i++) {
        if (r[i] >= 0) {
            int p = gbase[r[i]] + lpos[i];
            if (p < CAP) {
                int2 v; v.x = c[i]; v.y = s[i];
                pairs[(size_t)r[i] * CAP + p] = v;
            }
        }
    }
}

// ---------- per-bucket LDS histogram -> exact indeg (no global atomics) ----------
__global__ __launch_bounds__(1024) void k_hist(const int2* pairs, const int* cnt, int* indeg) {
    __shared__ int hist[RANGE64];
    int b = blockIdx.x;
    int c0 = b * RANGE64;
    int range = min(RANGE64, N_NODES - c0);
    for (int i = threadIdx.x; i < range; i += 1024) hist[i] = 0;
    __syncthreads();
    int n = min(cnt[b], CAP);
    const int2* pb = pairs + (size_t)b * CAP;
    for (int i = threadIdx.x; i < n; i += 1024)
        atomicAdd(&hist[pb[i].x - c0], 1);
    __syncthreads();
    for (int i = threadIdx.x; i < range; i += 1024) indeg[c0 + i] = hist[i];
}

__global__ void k_dis(const int* indeg, float* dis) {
    int i = blockIdx.x * 256 + threadIdx.x;
    if (i < N_NODES) dis[i] = rsqrtf((float)indeg[i] + 1.0f);
}

// ---------- prefix scan over PADDED degrees ((deg+7)&~7) ----------
__global__ __launch_bounds__(SCAN_B) void k_scan1(const int* indeg, int* incl, int* bsum) {
    __shared__ int tmp[SCAN_B];
    int i = blockIdx.x * SCAN_B + threadIdx.x;
    tmp[threadIdx.x] = (i < N_NODES) ? ((indeg[i] + 7) & ~7) : 0;
    __syncthreads();
    for (int d = 1; d < SCAN_B; d <<= 1) {
        int t = (threadIdx.x >= d) ? tmp[threadIdx.x - d] : 0;
        __syncthreads();
        tmp[threadIdx.x] += t;
        __syncthreads();
    }
    if (i < N_NODES) incl[i] = tmp[threadIdx.x];
    if (threadIdx.x == SCAN_B - 1) bsum[blockIdx.x] = tmp[threadIdx.x];
}

__global__ void k_scan2(int* bsum) {
    __shared__ int tmp[128];
    tmp[threadIdx.x] = (threadIdx.x < NBLK) ? bsum[threadIdx.x] : 0;
    __syncthreads();
    for (int d = 1; d < 128; d <<= 1) {
        int t = (threadIdx.x >= d) ? tmp[threadIdx.x - d] : 0;
        __syncthreads();
        tmp[threadIdx.x] += t;
        __syncthreads();
    }
    if (threadIdx.x < NBLK) bsum[threadIdx.x] = tmp[threadIdx.x];
}

__global__ __launch_bounds__(SCAN_B) void k_scan3(const int* indeg, const int* incl,
                                                  const int* bsum, int* offs) {
    int i = blockIdx.x * SCAN_B + threadIdx.x;
    if (i < N_NODES) {
        int pre = (blockIdx.x > 0) ? bsum[blockIdx.x - 1] : 0;
        offs[i] = incl[i] - ((indeg[i] + 7) & ~7) + pre;
    }
}

// ---------- per-bucket CSR placement via LDS cursors + inline padding ----------
// One block owns one bucket -> its srcs region [offs[c0], offs[c0+range]) is
// written by exactly one block (one XCD's L2) -> writeback ~= payload.
__global__ __launch_bounds__(1024) void k_place3(const int2* pairs, const int* cnt,
                                                 const int* offs, int* srcs) {
    __shared__ int cur[RANGE64];
    int b = blockIdx.x;
    int c0 = b * RANGE64;
    int range = min(RANGE64, N_NODES - c0);
    for (int i = threadIdx.x; i < range; i += 1024) cur[i] = 0;
    __syncthreads();
    int n = min(cnt[b], CAP);
    const int2* pb = pairs + (size_t)b * CAP;
    for (int i = threadIdx.x; i < n; i += 1024) {
        int2 v = pb[i];
        int p = offs[v.x] + atomicAdd(&cur[v.x - c0], 1);
        srcs[p] = v.y;
    }
    __syncthreads();
    for (int i = threadIdx.x; i < range; i += 1024) {
        int deg = cur[i];
        int pdeg = (deg + 7) & ~7;
        int o = offs[c0 + i];
        for (int k = deg; k < pdeg; k++) srcs[o + k] = N_NODES;
    }
}

// ---------- projection via MFMA: g[i,:] = fp8( dis[i] * (h[i,:] @ W) ) ----------
template <int K, typename IT>
__global__ __launch_bounds__(256) void k_proj(const IT* __restrict__ in,
                                              const float* __restrict__ W,
                                              const float* __restrict__ dis,
                                              unsigned char* __restrict__ g) {
    // zero the pad row (row N_NODES, 64 B)
    if (blockIdx.x == 0 && threadIdx.x < 16)
        ((unsigned*)g)[N_NODES * 16 + threadIdx.x] = 0u;
    const int NS = K / 32;
    int wave = threadIdx.x >> 6, lane = threadIdx.x & 63;
    int m = lane & 15, quad = lane >> 4;
    bf8_t Bf[NS][4];
#pragma unroll
    for (int s = 0; s < NS; s++)
#pragma unroll
        for (int t = 0; t < 4; t++)
#pragma unroll
            for (int j = 0; j < 8; j++)
                Bf[s][t][j] = f2bf(W[(s * 32 + quad * 8 + j) * 64 + t * 16 + m]);

    const int nchunks = N_NODES / 16;  // 6250
    const int stride = gridDim.x * 4;
    for (int chunk = blockIdx.x * 4 + wave; chunk < nchunks; chunk += stride) {
        int r0 = chunk * 16;
        const IT* src = in + (size_t)(r0 + m) * K + quad * 8;
        f4_t acc[4] = {{0.f, 0.f, 0.f, 0.f}, {0.f, 0.f, 0.f, 0.f},
                       {0.f, 0.f, 0.f, 0.f}, {0.f, 0.f, 0.f, 0.f}};
#pragma unroll
        for (int s = 0; s < NS; s++) {
            bf8_t a;
#pragma unroll
            for (int j = 0; j < 8; j++) a[j] = tobf(src[s * 32 + j]);
#pragma unroll
            for (int t = 0; t < 4; t++)
                acc[t] = __builtin_amdgcn_mfma_f32_16x16x32_bf16(a, Bf[s][t], acc[t], 0, 0, 0);
        }
        float dv[4];
#pragma unroll
        for (int i = 0; i < 4; i++) dv[i] = dis[r0 + quad * 4 + i];
#pragma unroll
        for (int t = 0; t < 4; t++)
#pragma unroll
            for (int i = 0; i < 4; i++)
                g[(size_t)(r0 + quad * 4 + i) * 64 + t * 16 + m] = f2fp8(dv[i] * acc[t][i]);
    }
}

// ---------- CSR aggregation: 8 edges per VMEM instruction ----------
template <bool RELU>
__global__ __launch_bounds__(256) void k_agg(const unsigned char* __restrict__ g,
                                             const int* __restrict__ srcs,
                                             const int* __restrict__ offs,
                                             const int* __restrict__ indeg,
                                             const float* __restrict__ dis,
                                             const float* __restrict__ b,
                                             unsigned short* __restrict__ out) {
    int node = (blockIdx.x * 256 + threadIdx.x) >> 6;
    int lane = threadIdx.x & 63;
    if (node >= N_NODES) return;
    int eg = lane >> 3, fg = lane & 7;
    int beg = offs[node];
    int deg = indeg[node];
    int pdeg = (deg + 7) & ~7;
    float acc[8] = {0.f, 0.f, 0.f, 0.f, 0.f, 0.f, 0.f, 0.f};
    if (eg == 0) {  // self loop once
        uint2 w = *(const uint2*)(g + (size_t)node * 64 + fg * 8);
        fp8acc4(acc, w.x);
        fp8acc4(acc + 4, w.y);
    }
    int d = 0;
    while (d < pdeg) {
        int cnt = min(pdeg - d, 64);  // multiple of 8
        int sv = (lane < cnt) ? srcs[beg + d + lane] : (int)N_NODES;
        for (int k = 0; k < cnt; k += 8) {
            int s = __shfl(sv, k + eg);
            uint2 w = *(const uint2*)(g + (size_t)s * 64 + fg * 8);
            fp8acc4(acc, w.x);
            fp8acc4(acc + 4, w.y);
        }
        d += cnt;
    }
#pragma unroll
    for (int msk = 8; msk <= 32; msk <<= 1)
#pragma unroll
        for (int j = 0; j < 8; j++) acc[j] += __shfl_xor(acc[j], msk);
    if (lane < 8) {
        float dv = dis[node];
        unsigned o[4];
#pragma unroll
        for (int p = 0; p < 4; p++) {
            float v0 = dv * acc[2 * p]     + b[lane * 8 + 2 * p];
            float v1 = dv * acc[2 * p + 1] + b[lane * 8 + 2 * p + 1];
            if (RELU) { v0 = fmaxf(v0, 0.f); v1 = fmaxf(v1, 0.f); }
            o[p] = ((unsigned)(unsigned short)f2bf(v1) << 16) | (unsigned short)f2bf(v0);
        }
        *(uint4*)((char*)out + (size_t)node * 128 + lane * 16) =
            make_uint4(o[0], o[1], o[2], o[3]);
    }
}

// ---------- pooling (batch sorted, bf16 in) ----------
__global__ void k_pool(const unsigned short* h, const int* bat, const int* flag,
                       float* sums, float* cnts) {
    const int R = 128;
    int wave = (blockIdx.x * 256 + threadIdx.x) >> 6;
    int lane = threadIdx.x & 63;
    int base = wave * R;
    if (base >= N_NODES) return;
    int f = *flag;
    int end = min(base + R, N_NODES);
    float acc = 0.f;
    int cur = ldidx(bat, f, (size_t)base);
    int cnt = 0;
    for (int r = base; r < end; r++) {
        int b = ldidx(bat, f, (size_t)r);
        if (b != cur) {
            if ((unsigned)cur < N_GRAPHS) {
                atomicAdd(&sums[cur * 64 + lane], acc);
                if (lane == 0) atomicAdd(&cnts[cur], (float)cnt);
            }
            acc = 0.f;
            cnt = 0;
            cur = b;
        }
        acc += bf2f(h[(size_t)r * 64 + lane]);
        cnt++;
    }
    if ((unsigned)cur < N_GRAPHS) {
        atomicAdd(&sums[cur * 64 + lane], acc);
        if (lane == 0) atomicAdd(&cnts[cur], (float)cnt);
    }
}

// ---------- head ----------
__global__ void k_head(const float* sums, const float* cnts, const float* Wlin,
                       const float* blin, float* out) {
    int t = blockIdx.x * 64 + threadIdx.x;
    if (t < N_GRAPHS * N_OUT) {
        int gph = t / N_OUT, o = t % N_OUT;
        float c = fmaxf(cnts[gph], 1.0f);
        float a = 0.f;
        for (int j = 0; j < HID; j++) a += sums[gph * 64 + j] * Wlin[j * N_OUT + o];
        out[t] = a / c + blin[o];
    }
}

extern "C" void kernel_launch(void* const* d_in, const int* in_sizes, int n_in,
                              void* d_out, int out_size, void* d_ws, size_t ws_size,
                              hipStream_t stream) {
    const float *x = nullptr, *W1 = nullptr, *W2 = nullptr, *W3 = nullptr, *Wlin = nullptr;
    const float *b1 = nullptr, *b2 = nullptr, *b3 = nullptr, *blin = nullptr;
    const int *ei = nullptr, *bat = nullptr;
    int n4096 = 0, n64 = 0;
    for (int i = 0; i < n_in; i++) {
        switch (in_sizes[i]) {
            case N_NODES * N_FEAT:  x    = (const float*)d_in[i]; break;
            case 2 * N_EDGES:       ei   = (const int*)d_in[i];   break;
            case N_NODES:           bat  = (const int*)d_in[i];   break;
            case N_FEAT * HID:      W1   = (const float*)d_in[i]; break;
            case HID * HID:
                if (n4096++ == 0) W2 = (const float*)d_in[i];
                else              W3 = (const float*)d_in[i];
                break;
            case HID * N_OUT:       Wlin = (const float*)d_in[i]; break;
            case HID:
                if (n64 == 0) b1 = (const float*)d_in[i];
                else if (n64 == 1) b2 = (const float*)d_in[i];
                else b3 = (const float*)d_in[i];
                n64++;
                break;
            case N_OUT:             blin = (const float*)d_in[i]; break;
            default: break;
        }
    }
    if (!x || !ei || !bat || !W1 || !W2 || !W3 || !Wlin || !b1 || !b2 || !b3 || !blin) {
        x    = (const float*)d_in[0];
        ei   = (const int*)d_in[1];
        bat  = (const int*)d_in[2];
        W1   = (const float*)d_in[3];  b1   = (const float*)d_in[4];
        W2   = (const float*)d_in[5];  b2   = (const float*)d_in[6];
        W3   = (const float*)d_in[7];  b3   = (const float*)d_in[8];
        Wlin = (const float*)d_in[9];  blin = (const float*)d_in[10];
    }
    float* out = (float*)d_out;  // fp32 output

    char* ws = (char*)d_ws;
    size_t off = 0;
    int2*           pairs = (int2*)(ws + off);           off += (size_t)NBUCK * CAP * 8;
    unsigned short* A     = (unsigned short*)(ws + off); off += (size_t)N_NODES * 64 * 2;
    unsigned char*  G     = (unsigned char*)(ws + off);  off += (size_t)(N_NODES + 1) * 64;
    float*          dis   = (float*)(ws + off);          off += (size_t)N_NODES * 4;
    float*          sums  = (float*)(ws + off);          off += (size_t)N_GRAPHS * HID * 4;
    float*          cnts  = (float*)(ws + off);          off += (size_t)N_GRAPHS * 4;
    int*            indeg = (int*)(ws + off);            off += (size_t)N_NODES * 4;
    int*            bcnt  = (int*)(ws + off);            off += NBUCK * 4;   // adjacent to indeg
    int*            incl  = (int*)(ws + off);            off += (size_t)N_NODES * 4;
    int*            offs  = (int*)(ws + off);            off += (size_t)N_NODES * 4;
    int*            bsum  = (int*)(ws + off);            off += 128 * 4;
    int*            srcs  = (int*)(ws + off);            off += (size_t)SRCS_CAP * 4;
    int*            flag  = (int*)(ws + off);            off += 4;

    const int nb_nodes  = (N_NODES + 255) / 256;
    const int nb_agg    = (N_NODES * 64 + 255) / 256;
    const int nb_bucket = (N_EDGES + 2047) / 2048;  // 782

    k_detect<<<1, 256, 0, stream>>>(ei, flag);

    // --- CSR build: bucket -> per-bucket hist/sort (XCD-mapping independent) ---
    hipMemsetAsync(bcnt, 0, NBUCK * 4, stream);
    k_bucket<<<nb_bucket, 256, 0, stream>>>(ei, flag, pairs, bcnt);
    k_hist<<<NBUCK, 1024, 0, stream>>>(pairs, bcnt, indeg);
    k_dis<<<nb_nodes, 256, 0, stream>>>(indeg, dis);
    k_scan1<<<NBLK, SCAN_B, 0, stream>>>(indeg, incl, bsum);
    k_scan2<<<1, 128, 0, stream>>>(bsum);
    k_scan3<<<NBLK, SCAN_B, 0, stream>>>(indeg, incl, bsum, offs);
    k_place3<<<NBUCK, 1024, 0, stream>>>(pairs, bcnt, offs, srcs);

    // conv1: x(fp32,128) -> G(fp8) -> A(bf16)
    k_proj<128, float><<<512, 256, 0, stream>>>(x, W1, dis, G);
    k_agg<true><<<nb_agg, 256, 0, stream>>>(G, srcs, offs, indeg, dis, b1, A);

    // conv2: A -> G -> A
    k_proj<64, unsigned short><<<512, 256, 0, stream>>>(A, W2, dis, G);
    k_agg<true><<<nb_agg, 256, 0, stream>>>(G, srcs, offs, indeg, dis, b2, A);

    // conv3: A -> G -> A (no relu)
    k_proj<64, unsigned short><<<512, 256, 0, stream>>>(A, W3, dis, G);
    k_agg<false><<<nb_agg, 256, 0, stream>>>(G, srcs, offs, indeg, dis, b3, A);

    // pool + head
    hipMemsetAsync(sums, 0, (size_t)(N_GRAPHS * HID + N_GRAPHS) * 4, stream);
    const int nwaves = (N_NODES + 127) / 128;
    k_pool<<<(nwaves * 64 + 255) / 256, 256, 0, stream>>>(A, bat, flag, sums, cnts);
    k_head<<<(N_GRAPHS * N_OUT + 63) / 64, 64, 0, stream>>>(sums, cnts, Wlin, blin, out);
}

// Round 15
// 383.941 us; speedup vs baseline: 1.2948x; 1.0046x over previous
//
#include <hip/hip_runtime.h>
#include <hip/hip_bf16.h>

#define N_NODES 100000
#define N_EDGES 1600000
#define N_FEAT 128
#define HID 64
#define N_GRAPHS 64
#define N_OUT 10
#define SCAN_B 1024
#define NBLK ((N_NODES + SCAN_B - 1) / SCAN_B)  // 98
#define NBUCK 64
#define RANGE64 ((N_NODES + NBUCK - 1) / NBUCK)  // 1563
#define CAP 40000
#define SRCS_CAP (N_EDGES + 8 * N_NODES)  // padded CSR upper bound
#define POOL_R 16

typedef __attribute__((ext_vector_type(8))) short bf8_t;   // 8 bf16 in 4 VGPRs
typedef __attribute__((ext_vector_type(4))) float f4_t;    // MFMA accumulator
typedef __attribute__((ext_vector_type(2))) float f2_t;

__device__ __forceinline__ short f2bf(float f) {
    __hip_bfloat16 h = __float2bfloat16(f);
    return *(short*)&h;
}
__device__ __forceinline__ float bf2f(unsigned short u) {
    unsigned v = ((unsigned)u) << 16;
    return __builtin_bit_cast(float, v);
}
__device__ __forceinline__ short tobf(float v) { return f2bf(v); }
__device__ __forceinline__ short tobf(unsigned short v) { return (short)v; }
__device__ __forceinline__ unsigned char f2fp8(float v) {
    int p = __builtin_amdgcn_cvt_pk_fp8_f32(v, v, 0, false);
    return (unsigned char)(p & 0xFF);
}
// decode 4 fp8 bytes (one dword) into acc[0..3] via 2 pk-converts
__device__ __forceinline__ void fp8acc4(float* acc, unsigned w) {
    f2_t lo = __builtin_amdgcn_cvt_pk_f32_fp8((int)w, false);
    f2_t hi = __builtin_amdgcn_cvt_pk_f32_fp8((int)w, true);
    acc[0] += lo[0]; acc[1] += lo[1]; acc[2] += hi[0]; acc[3] += hi[1];
}

// ---------- index dtype probe ----------
__global__ void k_detect(const int* raw, int* flag) {
    __shared__ int any;
    if (threadIdx.x == 0) any = 0;
    __syncthreads();
    int v = raw[2 * threadIdx.x + 1] | raw[2 * (threadIdx.x + 256) + 1] |
            raw[2 * (threadIdx.x + 512) + 1] | raw[2 * (threadIdx.x + 768) + 1];
    if (v != 0) any = 1;
    __syncthreads();
    if (threadIdx.x == 0) *flag = (any == 0) ? 1 : 0;
}

__device__ __forceinline__ int ldidx(const int* raw, int f, size_t i) {
    return f ? raw[2 * i] : raw[i];
}

// ---------- phase 1: bin edges into 64 col-range buckets ----------
__global__ __launch_bounds__(256) void k_bucket(const int* ei, const int* flag,
                                                int2* pairs, int* cnt) {
    __shared__ int lcnt[NBUCK];
    __shared__ int gbase[NBUCK];
    int f = *flag;
    if (threadIdx.x < NBUCK) lcnt[threadIdx.x] = 0;
    __syncthreads();
    int base = blockIdx.x * 2048;
    int r[8], lpos[8], c[8], s[8];
#pragma unroll
    for (int i = 0; i < 8; i++) {
        int e = base + i * 256 + threadIdx.x;
        r[i] = -1;
        if (e < N_EDGES) {
            c[i] = ldidx(ei, f, (size_t)N_EDGES + e);
            s[i] = ldidx(ei, f, (size_t)e);
            if ((unsigned)c[i] < N_NODES && (unsigned)s[i] < N_NODES) {
                r[i] = c[i] / RANGE64;
                lpos[i] = atomicAdd(&lcnt[r[i]], 1);
            }
        }
    }
    __syncthreads();
    if (threadIdx.x < NBUCK && lcnt[threadIdx.x] > 0)
        gbase[threadIdx.x] = atomicAdd(&cnt[threadIdx.x], lcnt[threadIdx.x]);
    __syncthreads();
#pragma unroll
    for (int i = 0; i < 8; i++) {
        if (r[i] >= 0) {
            int p = gbase[r[i]] + lpos[i];
            if (p < CAP) {
                int2 v; v.x = c[i]; v.y = s[i];
                pairs[(size_t)r[i] * CAP + p] = v;
            }
        }
    }
}

// ---------- per-bucket LDS histogram -> exact indeg (no global atomics) ----------
__global__ __launch_bounds__(1024) void k_hist(const int2* pairs, const int* cnt, int* indeg) {
    __shared__ int hist[RANGE64];
    int b = blockIdx.x;
    int c0 = b * RANGE64;
    int range = min(RANGE64, N_NODES - c0);
    for (int i = threadIdx.x; i < range; i += 1024) hist[i] = 0;
    __syncthreads();
    int n = min(cnt[b], CAP);
    const int2* pb = pairs + (size_t)b * CAP;
    for (int i = threadIdx.x; i < n; i += 1024)
        atomicAdd(&hist[pb[i].x - c0], 1);
    __syncthreads();
    for (int i = threadIdx.x; i < range; i += 1024) indeg[c0 + i] = hist[i];
}

__global__ void k_dis(const int* indeg, float* dis) {
    int i = blockIdx.x * 256 + threadIdx.x;
    if (i < N_NODES) dis[i] = rsqrtf((float)indeg[i] + 1.0f);
}

// ---------- prefix scan over PADDED degrees ((deg+7)&~7) ----------
__global__ __launch_bounds__(SCAN_B) void k_scan1(const int* indeg, int* incl, int* bsum) {
    __shared__ int tmp[SCAN_B];
    int i = blockIdx.x * SCAN_B + threadIdx.x;
    tmp[threadIdx.x] = (i < N_NODES) ? ((indeg[i] + 7) & ~7) : 0;
    __syncthreads();
    for (int d = 1; d < SCAN_B; d <<= 1) {
        int t = (threadIdx.x >= d) ? tmp[threadIdx.x - d] : 0;
        __syncthreads();
        tmp[threadIdx.x] += t;
        __syncthreads();
    }
    if (i < N_NODES) incl[i] = tmp[threadIdx.x];
    if (threadIdx.x == SCAN_B - 1) bsum[blockIdx.x] = tmp[threadIdx.x];
}

__global__ void k_scan2(int* bsum) {
    __shared__ int tmp[128];
    tmp[threadIdx.x] = (threadIdx.x < NBLK) ? bsum[threadIdx.x] : 0;
    __syncthreads();
    for (int d = 1; d < 128; d <<= 1) {
        int t = (threadIdx.x >= d) ? tmp[threadIdx.x - d] : 0;
        __syncthreads();
        tmp[threadIdx.x] += t;
        __syncthreads();
    }
    if (threadIdx.x < NBLK) bsum[threadIdx.x] = tmp[threadIdx.x];
}

__global__ __launch_bounds__(SCAN_B) void k_scan3(const int* indeg, const int* incl,
                                                  const int* bsum, int* offs) {
    int i = blockIdx.x * SCAN_B + threadIdx.x;
    if (i < N_NODES) {
        int pre = (blockIdx.x > 0) ? bsum[blockIdx.x - 1] : 0;
        offs[i] = incl[i] - ((indeg[i] + 7) & ~7) + pre;
    }
}

// ---------- per-bucket CSR placement via LDS cursors + inline padding ----------
__global__ __launch_bounds__(1024) void k_place3(const int2* pairs, const int* cnt,
                                                 const int* offs, int* srcs) {
    __shared__ int cur[RANGE64];
    int b = blockIdx.x;
    int c0 = b * RANGE64;
    int range = min(RANGE64, N_NODES - c0);
    for (int i = threadIdx.x; i < range; i += 1024) cur[i] = 0;
    __syncthreads();
    int n = min(cnt[b], CAP);
    const int2* pb = pairs + (size_t)b * CAP;
    for (int i = threadIdx.x; i < n; i += 1024) {
        int2 v = pb[i];
        int p = offs[v.x] + atomicAdd(&cur[v.x - c0], 1);
        srcs[p] = v.y;
    }
    __syncthreads();
    for (int i = threadIdx.x; i < range; i += 1024) {
        int deg = cur[i];
        int pdeg = (deg + 7) & ~7;
        int o = offs[c0 + i];
        for (int k = deg; k < pdeg; k++) srcs[o + k] = N_NODES;
    }
}

// ---------- projection via MFMA: g[i,:] = fp8( dis[i] * (h[i,:] @ W) ) ----------
template <int K, typename IT>
__global__ __launch_bounds__(256) void k_proj(const IT* __restrict__ in,
                                              const float* __restrict__ W,
                                              const float* __restrict__ dis,
                                              unsigned char* __restrict__ g) {
    // zero the pad row (row N_NODES, 64 B)
    if (blockIdx.x == 0 && threadIdx.x < 16)
        ((unsigned*)g)[N_NODES * 16 + threadIdx.x] = 0u;
    const int NS = K / 32;
    int wave = threadIdx.x >> 6, lane = threadIdx.x & 63;
    int m = lane & 15, quad = lane >> 4;
    bf8_t Bf[NS][4];
#pragma unroll
    for (int s = 0; s < NS; s++)
#pragma unroll
        for (int t = 0; t < 4; t++)
#pragma unroll
            for (int j = 0; j < 8; j++)
                Bf[s][t][j] = f2bf(W[(s * 32 + quad * 8 + j) * 64 + t * 16 + m]);

    const int nchunks = N_NODES / 16;  // 6250
    const int stride = gridDim.x * 4;
    for (int chunk = blockIdx.x * 4 + wave; chunk < nchunks; chunk += stride) {
        int r0 = chunk * 16;
        const IT* src = in + (size_t)(r0 + m) * K + quad * 8;
        f4_t acc[4] = {{0.f, 0.f, 0.f, 0.f}, {0.f, 0.f, 0.f, 0.f},
                       {0.f, 0.f, 0.f, 0.f}, {0.f, 0.f, 0.f, 0.f}};
#pragma unroll
        for (int s = 0; s < NS; s++) {
            bf8_t a;
#pragma unroll
            for (int j = 0; j < 8; j++) a[j] = tobf(src[s * 32 + j]);
#pragma unroll
            for (int t = 0; t < 4; t++)
                acc[t] = __builtin_amdgcn_mfma_f32_16x16x32_bf16(a, Bf[s][t], acc[t], 0, 0, 0);
        }
        float dv[4];
#pragma unroll
        for (int i = 0; i < 4; i++) dv[i] = dis[r0 + quad * 4 + i];
#pragma unroll
        for (int t = 0; t < 4; t++)
#pragma unroll
            for (int i = 0; i < 4; i++)
                g[(size_t)(r0 + quad * 4 + i) * 64 + t * 16 + m] = f2fp8(dv[i] * acc[t][i]);
    }
}

// ---------- CSR aggregation: 8 edges per VMEM instruction ----------
template <bool RELU>
__global__ __launch_bounds__(256) void k_agg(const unsigned char* __restrict__ g,
                                             const int* __restrict__ srcs,
                                             const int* __restrict__ offs,
                                             const int* __restrict__ indeg,
                                             const float* __restrict__ dis,
                                             const float* __restrict__ b,
                                             unsigned short* __restrict__ out) {
    int node = (blockIdx.x * 256 + threadIdx.x) >> 6;
    int lane = threadIdx.x & 63;
    if (node >= N_NODES) return;
    int eg = lane >> 3, fg = lane & 7;
    int beg = offs[node];
    int deg = indeg[node];
    int pdeg = (deg + 7) & ~7;
    float acc[8] = {0.f, 0.f, 0.f, 0.f, 0.f, 0.f, 0.f, 0.f};
    if (eg == 0) {  // self loop once
        uint2 w = *(const uint2*)(g + (size_t)node * 64 + fg * 8);
        fp8acc4(acc, w.x);
        fp8acc4(acc + 4, w.y);
    }
    int d = 0;
    while (d < pdeg) {
        int cnt = min(pdeg - d, 64);  // multiple of 8
        int sv = (lane < cnt) ? srcs[beg + d + lane] : (int)N_NODES;
        for (int k = 0; k < cnt; k += 8) {
            int s = __shfl(sv, k + eg);
            uint2 w = *(const uint2*)(g + (size_t)s * 64 + fg * 8);
            fp8acc4(acc, w.x);
            fp8acc4(acc + 4, w.y);
        }
        d += cnt;
    }
#pragma unroll
    for (int msk = 8; msk <= 32; msk <<= 1)
#pragma unroll
        for (int j = 0; j < 8; j++) acc[j] += __shfl_xor(acc[j], msk);
    if (lane < 8) {
        float dv = dis[node];
        unsigned o[4];
#pragma unroll
        for (int p = 0; p < 4; p++) {
            float v0 = dv * acc[2 * p]     + b[lane * 8 + 2 * p];
            float v1 = dv * acc[2 * p + 1] + b[lane * 8 + 2 * p + 1];
            if (RELU) { v0 = fmaxf(v0, 0.f); v1 = fmaxf(v1, 0.f); }
            o[p] = ((unsigned)(unsigned short)f2bf(v1) << 16) | (unsigned short)f2bf(v0);
        }
        *(uint4*)((char*)out + (size_t)node * 128 + lane * 16) =
            make_uint4(o[0], o[1], o[2], o[3]);
    }
}

// ---------- pooling (batch sorted, bf16 in); R=16 rows/wave for occupancy ----------
__global__ void k_pool(const unsigned short* h, const int* bat, const int* flag,
                       float* sums, float* cnts) {
    int wave = (blockIdx.x * 256 + threadIdx.x) >> 6;
    int lane = threadIdx.x & 63;
    int base = wave * POOL_R;
    if (base >= N_NODES) return;
    int f = *flag;
    int end = min(base + POOL_R, N_NODES);
    float acc = 0.f;
    int cur = ldidx(bat, f, (size_t)base);
    int cnt = 0;
    for (int r = base; r < end; r++) {
        int b = ldidx(bat, f, (size_t)r);
        if (b != cur) {
            if ((unsigned)cur < N_GRAPHS) {
                atomicAdd(&sums[cur * 64 + lane], acc);
                if (lane == 0) atomicAdd(&cnts[cur], (float)cnt);
            }
            acc = 0.f;
            cnt = 0;
            cur = b;
        }
        acc += bf2f(h[(size_t)r * 64 + lane]);
        cnt++;
    }
    if ((unsigned)cur < N_GRAPHS) {
        atomicAdd(&sums[cur * 64 + lane], acc);
        if (lane == 0) atomicAdd(&cnts[cur], (float)cnt);
    }
}

// ---------- head ----------
__global__ void k_head(const float* sums, const float* cnts, const float* Wlin,
                       const float* blin, float* out) {
    int t = blockIdx.x * 64 + threadIdx.x;
    if (t < N_GRAPHS * N_OUT) {
        int gph = t / N_OUT, o = t % N_OUT;
        float c = fmaxf(cnts[gph], 1.0f);
        float a = 0.f;
        for (int j = 0; j < HID; j++) a += sums[gph * 64 + j] * Wlin[j * N_OUT + o];
        out[t] = a / c + blin[o];
    }
}

extern "C" void kernel_launch(void* const* d_in, const int* in_sizes, int n_in,
                              void* d_out, int out_size, void* d_ws, size_t ws_size,
                              hipStream_t stream) {
    const float *x = nullptr, *W1 = nullptr, *W2 = nullptr, *W3 = nullptr, *Wlin = nullptr;
    const float *b1 = nullptr, *b2 = nullptr, *b3 = nullptr, *blin = nullptr;
    const int *ei = nullptr, *bat = nullptr;
    int n4096 = 0, n64 = 0;
    for (int i = 0; i < n_in; i++) {
        switch (in_sizes[i]) {
            case N_NODES * N_FEAT:  x    = (const float*)d_in[i]; break;
            case 2 * N_EDGES:       ei   = (const int*)d_in[i];   break;
            case N_NODES:           bat  = (const int*)d_in[i];   break;
            case N_FEAT * HID:      W1   = (const float*)d_in[i]; break;
            case HID * HID:
                if (n4096++ == 0) W2 = (const float*)d_in[i];
                else              W3 = (const float*)d_in[i];
                break;
            case HID * N_OUT:       Wlin = (const float*)d_in[i]; break;
            case HID:
                if (n64 == 0) b1 = (const float*)d_in[i];
                else if (n64 == 1) b2 = (const float*)d_in[i];
                else b3 = (const float*)d_in[i];
                n64++;
                break;
            case N_OUT:             blin = (const float*)d_in[i]; break;
            default: break;
        }
    }
    if (!x || !ei || !bat || !W1 || !W2 || !W3 || !Wlin || !b1 || !b2 || !b3 || !blin) {
        x    = (const float*)d_in[0];
        ei   = (const int*)d_in[1];
        bat  = (const int*)d_in[2];
        W1   = (const float*)d_in[3];  b1   = (const float*)d_in[4];
        W2   = (const float*)d_in[5];  b2   = (const float*)d_in[6];
        W3   = (const float*)d_in[7];  b3   = (const float*)d_in[8];
        Wlin = (const float*)d_in[9];  blin = (const float*)d_in[10];
    }
    float* out = (float*)d_out;  // fp32 output

    char* ws = (char*)d_ws;
    size_t off = 0;
    int2*           pairs = (int2*)(ws + off);           off += (size_t)NBUCK * CAP * 8;
    unsigned short* A     = (unsigned short*)(ws + off); off += (size_t)N_NODES * 64 * 2;
    unsigned char*  G     = (unsigned char*)(ws + off);  off += (size_t)(N_NODES + 1) * 64;
    float*          dis   = (float*)(ws + off);          off += (size_t)N_NODES * 4;
    float*          sums  = (float*)(ws + off);          off += (size_t)N_GRAPHS * HID * 4;
    float*          cnts  = (float*)(ws + off);          off += (size_t)N_GRAPHS * 4;
    int*            indeg = (int*)(ws + off);            off += (size_t)N_NODES * 4;
    int*            bcnt  = (int*)(ws + off);            off += NBUCK * 4;
    int*            incl  = (int*)(ws + off);            off += (size_t)N_NODES * 4;
    int*            offs  = (int*)(ws + off);            off += (size_t)N_NODES * 4;
    int*            bsum  = (int*)(ws + off);            off += 128 * 4;
    int*            srcs  = (int*)(ws + off);            off += (size_t)SRCS_CAP * 4;
    int*            flag  = (int*)(ws + off);            off += 4;

    const int nb_nodes  = (N_NODES + 255) / 256;
    const int nb_agg    = (N_NODES * 64 + 255) / 256;
    const int nb_bucket = (N_EDGES + 2047) / 2048;  // 782

    k_detect<<<1, 256, 0, stream>>>(ei, flag);

    // --- CSR build: bucket -> per-bucket hist/sort (XCD-mapping independent) ---
    hipMemsetAsync(bcnt, 0, NBUCK * 4, stream);
    k_bucket<<<nb_bucket, 256, 0, stream>>>(ei, flag, pairs, bcnt);
    k_hist<<<NBUCK, 1024, 0, stream>>>(pairs, bcnt, indeg);
    k_dis<<<nb_nodes, 256, 0, stream>>>(indeg, dis);
    k_scan1<<<NBLK, SCAN_B, 0, stream>>>(indeg, incl, bsum);
    k_scan2<<<1, 128, 0, stream>>>(bsum);
    k_scan3<<<NBLK, SCAN_B, 0, stream>>>(indeg, incl, bsum, offs);
    k_place3<<<NBUCK, 1024, 0, stream>>>(pairs, bcnt, offs, srcs);

    // conv1: x(fp32,128) -> G(fp8) -> A(bf16)
    k_proj<128, float><<<512, 256, 0, stream>>>(x, W1, dis, G);
    k_agg<true><<<nb_agg, 256, 0, stream>>>(G, srcs, offs, indeg, dis, b1, A);

    // conv2: A -> G -> A
    k_proj<64, unsigned short><<<512, 256, 0, stream>>>(A, W2, dis, G);
    k_agg<true><<<nb_agg, 256, 0, stream>>>(G, srcs, offs, indeg, dis, b2, A);

    // conv3: A -> G -> A (no relu)
    k_proj<64, unsigned short><<<512, 256, 0, stream>>>(A, W3, dis, G);
    k_agg<false><<<nb_agg, 256, 0, stream>>>(G, srcs, offs, indeg, dis, b3, A);

    // pool + head
    hipMemsetAsync(sums, 0, (size_t)(N_GRAPHS * HID + N_GRAPHS) * 4, stream);
    const int nwaves = (N_NODES + POOL_R - 1) / POOL_R;  // 6250
    k_pool<<<(nwaves * 64 + 255) / 256, 256, 0, stream>>>(A, bat, flag, sums, cnts);
    k_head<<<(N_GRAPHS * N_OUT + 63) / 64, 64, 0, stream>>>(sums, cnts, Wlin, blin, out);
}

// Round 16
// 364.228 us; speedup vs baseline: 1.3648x; 1.0541x over previous
//
#include <hip/hip_runtime.h>
#include <hip/hip_bf16.h>

#define N_NODES 100000
#define N_EDGES 1600000
#define N_FEAT 128
#define HID 64
#define N_GRAPHS 64
#define N_OUT 10
#define SCAN_B 1024
#define NBLK ((N_NODES + SCAN_B - 1) / SCAN_B)  // 98
#define NBUCK 64
#define RANGE64 ((N_NODES + NBUCK - 1) / NBUCK)  // 1563
#define CAP 40000
#define SRCS_CAP (N_EDGES + 8 * N_NODES)  // padded CSR upper bound

typedef __attribute__((ext_vector_type(8))) short bf8_t;   // 8 bf16 in 4 VGPRs
typedef __attribute__((ext_vector_type(4))) float f4_t;    // MFMA accumulator
typedef __attribute__((ext_vector_type(2))) float f2_t;

__device__ __forceinline__ short f2bf(float f) {
    __hip_bfloat16 h = __float2bfloat16(f);
    return *(short*)&h;
}
__device__ __forceinline__ float bf2f(unsigned short u) {
    unsigned v = ((unsigned)u) << 16;
    return __builtin_bit_cast(float, v);
}
__device__ __forceinline__ short tobf(float v) { return f2bf(v); }
__device__ __forceinline__ short tobf(unsigned short v) { return (short)v; }
__device__ __forceinline__ unsigned char f2fp8(float v) {
    int p = __builtin_amdgcn_cvt_pk_fp8_f32(v, v, 0, false);
    return (unsigned char)(p & 0xFF);
}
// decode one dword of fp8 into two f2_t accumulators (v_pk_add_f32-friendly)
__device__ __forceinline__ void fp8acc2(f2_t* acc2, unsigned w) {
    acc2[0] += __builtin_amdgcn_cvt_pk_f32_fp8((int)w, false);
    acc2[1] += __builtin_amdgcn_cvt_pk_f32_fp8((int)w, true);
}

__device__ __forceinline__ int ldidx(const int* raw, int f, size_t i) {
    return f ? raw[2 * i] : raw[i];
}

// ---------- index dtype probe + workspace zeroing (merged) ----------
__global__ void k_detect(const int* raw, int* flag, int* bcnt, float* sums, float* cnts) {
    __shared__ int any;
    if (threadIdx.x == 0) any = 0;
    __syncthreads();
    int v = raw[2 * threadIdx.x + 1] | raw[2 * (threadIdx.x + 256) + 1] |
            raw[2 * (threadIdx.x + 512) + 1] | raw[2 * (threadIdx.x + 768) + 1];
    if (v != 0) any = 1;
    __syncthreads();
    if (threadIdx.x == 0) *flag = (any == 0) ? 1 : 0;
    for (int i = threadIdx.x; i < NBUCK; i += 256) bcnt[i] = 0;
    for (int i = threadIdx.x; i < N_GRAPHS * HID; i += 256) sums[i] = 0.f;
    for (int i = threadIdx.x; i < N_GRAPHS; i += 256) cnts[i] = 0.f;
}

// ---------- phase 1: bin edges into 64 col-range buckets ----------
__global__ __launch_bounds__(256) void k_bucket(const int* ei, const int* flag,
                                                int2* pairs, int* cnt) {
    __shared__ int lcnt[NBUCK];
    __shared__ int gbase[NBUCK];
    int f = *flag;
    if (threadIdx.x < NBUCK) lcnt[threadIdx.x] = 0;
    __syncthreads();
    int base = blockIdx.x * 2048;
    int r[8], lpos[8], c[8], s[8];
#pragma unroll
    for (int i = 0; i < 8; i++) {
        int e = base + i * 256 + threadIdx.x;
        r[i] = -1;
        if (e < N_EDGES) {
            c[i] = ldidx(ei, f, (size_t)N_EDGES + e);
            s[i] = ldidx(ei, f, (size_t)e);
            if ((unsigned)c[i] < N_NODES && (unsigned)s[i] < N_NODES) {
                r[i] = c[i] / RANGE64;
                lpos[i] = atomicAdd(&lcnt[r[i]], 1);
            }
        }
    }
    __syncthreads();
    if (threadIdx.x < NBUCK && lcnt[threadIdx.x] > 0)
        gbase[threadIdx.x] = atomicAdd(&cnt[threadIdx.x], lcnt[threadIdx.x]);
    __syncthreads();
#pragma unroll
    for (int i = 0; i < 8; i++) {
        if (r[i] >= 0) {
            int p = gbase[r[i]] + lpos[i];
            if (p < CAP) {
                int2 v; v.x = c[i]; v.y = s[i];
                pairs[(size_t)r[i] * CAP + p] = v;
            }
        }
    }
}

// ---------- per-bucket LDS histogram -> indeg + dis (merged) ----------
__global__ __launch_bounds__(1024) void k_hist(const int2* pairs, const int* cnt,
                                               int* indeg, float* dis) {
    __shared__ int hist[RANGE64];
    int b = blockIdx.x;
    int c0 = b * RANGE64;
    int range = min(RANGE64, N_NODES - c0);
    for (int i = threadIdx.x; i < range; i += 1024) hist[i] = 0;
    __syncthreads();
    int n = min(cnt[b], CAP);
    const int2* pb = pairs + (size_t)b * CAP;
    for (int i = threadIdx.x; i < n; i += 1024)
        atomicAdd(&hist[pb[i].x - c0], 1);
    __syncthreads();
    for (int i = threadIdx.x; i < range; i += 1024) {
        int d = hist[i];
        indeg[c0 + i] = d;
        dis[c0 + i] = rsqrtf((float)d + 1.0f);
    }
}

// ---------- prefix scan over PADDED degrees ((deg+7)&~7) ----------
__global__ __launch_bounds__(SCAN_B) void k_scan1(const int* indeg, int* incl, int* bsum) {
    __shared__ int tmp[SCAN_B];
    int i = blockIdx.x * SCAN_B + threadIdx.x;
    tmp[threadIdx.x] = (i < N_NODES) ? ((indeg[i] + 7) & ~7) : 0;
    __syncthreads();
    for (int d = 1; d < SCAN_B; d <<= 1) {
        int t = (threadIdx.x >= d) ? tmp[threadIdx.x - d] : 0;
        __syncthreads();
        tmp[threadIdx.x] += t;
        __syncthreads();
    }
    if (i < N_NODES) incl[i] = tmp[threadIdx.x];
    if (threadIdx.x == SCAN_B - 1) bsum[blockIdx.x] = tmp[threadIdx.x];
}

__global__ void k_scan2(int* bsum) {
    __shared__ int tmp[128];
    tmp[threadIdx.x] = (threadIdx.x < NBLK) ? bsum[threadIdx.x] : 0;
    __syncthreads();
    for (int d = 1; d < 128; d <<= 1) {
        int t = (threadIdx.x >= d) ? tmp[threadIdx.x - d] : 0;
        __syncthreads();
        tmp[threadIdx.x] += t;
        __syncthreads();
    }
    if (threadIdx.x < NBLK) bsum[threadIdx.x] = tmp[threadIdx.x];
}

__global__ __launch_bounds__(SCAN_B) void k_scan3(const int* indeg, const int* incl,
                                                  const int* bsum, int* offs) {
    int i = blockIdx.x * SCAN_B + threadIdx.x;
    if (i < N_NODES) {
        int pre = (blockIdx.x > 0) ? bsum[blockIdx.x - 1] : 0;
        offs[i] = incl[i] - ((indeg[i] + 7) & ~7) + pre;
    }
}

// ---------- per-bucket CSR placement via LDS cursors + inline padding ----------
__global__ __launch_bounds__(1024) void k_place3(const int2* pairs, const int* cnt,
                                                 const int* offs, int* srcs) {
    __shared__ int cur[RANGE64];
    int b = blockIdx.x;
    int c0 = b * RANGE64;
    int range = min(RANGE64, N_NODES - c0);
    for (int i = threadIdx.x; i < range; i += 1024) cur[i] = 0;
    __syncthreads();
    int n = min(cnt[b], CAP);
    const int2* pb = pairs + (size_t)b * CAP;
    for (int i = threadIdx.x; i < n; i += 1024) {
        int2 v = pb[i];
        int p = offs[v.x] + atomicAdd(&cur[v.x - c0], 1);
        srcs[p] = v.y;
    }
    __syncthreads();
    for (int i = threadIdx.x; i < range; i += 1024) {
        int deg = cur[i];
        int pdeg = (deg + 7) & ~7;
        int o = offs[c0 + i];
        for (int k = deg; k < pdeg; k++) srcs[o + k] = N_NODES;
    }
}

// ---------- projection via MFMA: g[i,:] = fp8( dis[i] * (h[i,:] @ W) ) ----------
template <int K, typename IT>
__global__ __launch_bounds__(256) void k_proj(const IT* __restrict__ in,
                                              const float* __restrict__ W,
                                              const float* __restrict__ dis,
                                              unsigned char* __restrict__ g) {
    // zero the pad row (row N_NODES, 64 B)
    if (blockIdx.x == 0 && threadIdx.x < 16)
        ((unsigned*)g)[N_NODES * 16 + threadIdx.x] = 0u;
    const int NS = K / 32;
    int wave = threadIdx.x >> 6, lane = threadIdx.x & 63;
    int m = lane & 15, quad = lane >> 4;
    bf8_t Bf[NS][4];
#pragma unroll
    for (int s = 0; s < NS; s++)
#pragma unroll
        for (int t = 0; t < 4; t++)
#pragma unroll
            for (int j = 0; j < 8; j++)
                Bf[s][t][j] = f2bf(W[(s * 32 + quad * 8 + j) * 64 + t * 16 + m]);

    const int nchunks = N_NODES / 16;  // 6250
    const int stride = gridDim.x * 4;
    for (int chunk = blockIdx.x * 4 + wave; chunk < nchunks; chunk += stride) {
        int r0 = chunk * 16;
        const IT* src = in + (size_t)(r0 + m) * K + quad * 8;
        f4_t acc[4] = {{0.f, 0.f, 0.f, 0.f}, {0.f, 0.f, 0.f, 0.f},
                       {0.f, 0.f, 0.f, 0.f}, {0.f, 0.f, 0.f, 0.f}};
#pragma unroll
        for (int s = 0; s < NS; s++) {
            bf8_t a;
#pragma unroll
            for (int j = 0; j < 8; j++) a[j] = tobf(src[s * 32 + j]);
#pragma unroll
            for (int t = 0; t < 4; t++)
                acc[t] = __builtin_amdgcn_mfma_f32_16x16x32_bf16(a, Bf[s][t], acc[t], 0, 0, 0);
        }
        float dv[4];
#pragma unroll
        for (int i = 0; i < 4; i++) dv[i] = dis[r0 + quad * 4 + i];
#pragma unroll
        for (int t = 0; t < 4; t++)
#pragma unroll
            for (int i = 0; i < 4; i++)
                g[(size_t)(r0 + quad * 4 + i) * 64 + t * 16 + m] = f2fp8(dv[i] * acc[t][i]);
    }
}

// ---------- CSR aggregation: 8 edges per VMEM instruction, packed f32 adds ----------
template <bool RELU>
__global__ __launch_bounds__(256) void k_agg(const unsigned char* __restrict__ g,
                                             const int* __restrict__ srcs,
                                             const int* __restrict__ offs,
                                             const int* __restrict__ indeg,
                                             const float* __restrict__ dis,
                                             const float* __restrict__ b,
                                             unsigned short* __restrict__ out) {
    int node = (blockIdx.x * 256 + threadIdx.x) >> 6;
    int lane = threadIdx.x & 63;
    if (node >= N_NODES) return;
    int eg = lane >> 3, fg = lane & 7;
    int beg = offs[node];
    int deg = indeg[node];
    int pdeg = (deg + 7) & ~7;
    f2_t acc2[4] = {{0.f, 0.f}, {0.f, 0.f}, {0.f, 0.f}, {0.f, 0.f}};
    if (eg == 0) {  // self loop once
        uint2 w = *(const uint2*)(g + (size_t)node * 64 + fg * 8);
        fp8acc2(acc2, w.x);
        fp8acc2(acc2 + 2, w.y);
    }
    int d = 0;
    while (d < pdeg) {
        int cnt = min(pdeg - d, 64);  // multiple of 8
        int sv = (lane < cnt) ? srcs[beg + d + lane] : (int)N_NODES;
        for (int k = 0; k < cnt; k += 8) {
            int s = __shfl(sv, k + eg);
            uint2 w = *(const uint2*)(g + (size_t)s * 64 + fg * 8);
            fp8acc2(acc2, w.x);
            fp8acc2(acc2 + 2, w.y);
        }
        d += cnt;
    }
    // flatten (same feature order: acc[j] = feature fg*8+j)
    float acc[8];
#pragma unroll
    for (int j = 0; j < 8; j++) acc[j] = acc2[j >> 1][j & 1];
    // reduce across the 8 edge slots (lanes with same fg)
#pragma unroll
    for (int msk = 8; msk <= 32; msk <<= 1)
#pragma unroll
        for (int j = 0; j < 8; j++) acc[j] += __shfl_xor(acc[j], msk);
    if (lane < 8) {
        float dv = dis[node];
        unsigned o[4];
#pragma unroll
        for (int p = 0; p < 4; p++) {
            float v0 = dv * acc[2 * p]     + b[lane * 8 + 2 * p];
            float v1 = dv * acc[2 * p + 1] + b[lane * 8 + 2 * p + 1];
            if (RELU) { v0 = fmaxf(v0, 0.f); v1 = fmaxf(v1, 0.f); }
            o[p] = ((unsigned)(unsigned short)f2bf(v1) << 16) | (unsigned short)f2bf(v0);
        }
        *(uint4*)((char*)out + (size_t)node * 128 + lane * 16) =
            make_uint4(o[0], o[1], o[2], o[3]);
    }
}

// ---------- pooling: 4 blocks per graph, binary-search boundaries, LDS reduce ----------
// batch is sorted; graph g's rows are contiguous. One atomicAdd per lane per block.
__global__ __launch_bounds__(256) void k_pool(const unsigned short* h, const int* bat,
                                              const int* flag, float* sums, float* cnts) {
    __shared__ int sb[2];
    __shared__ float red[4][64];
    int g = blockIdx.x >> 2;
    int q = blockIdx.x & 3;
    if (threadIdx.x == 0) {
        int f = *flag;
        int lo = 0, hi = N_NODES;
        while (lo < hi) { int mid = (lo + hi) >> 1; if (ldidx(bat, f, (size_t)mid) < g) lo = mid + 1; else hi = mid; }
        sb[0] = lo;
        hi = N_NODES;
        while (lo < hi) { int mid = (lo + hi) >> 1; if (ldidx(bat, f, (size_t)mid) < g + 1) lo = mid + 1; else hi = mid; }
        sb[1] = lo;
    }
    __syncthreads();
    int gs = sb[0], ge = sb[1];
    int len = ge - gs;
    if (q == 0 && threadIdx.x == 0) cnts[g] = (float)len;
    if (len == 0) return;
    int qlen = (len + 3) >> 2;
    int beg = gs + q * qlen, end = min(ge, beg + qlen);
    int wave = threadIdx.x >> 6, lane = threadIdx.x & 63;
    float acc = 0.f;
    for (int r = beg + wave; r < end; r += 4)
        acc += bf2f(h[(size_t)r * 64 + lane]);
    red[wave][lane] = acc;
    __syncthreads();
    if (threadIdx.x < 64) {
        float v = red[0][threadIdx.x] + red[1][threadIdx.x] +
                  red[2][threadIdx.x] + red[3][threadIdx.x];
        atomicAdd(&sums[g * 64 + threadIdx.x], v);
    }
}

// ---------- head ----------
__global__ void k_head(const float* sums, const float* cnts, const float* Wlin,
                       const float* blin, float* out) {
    int t = blockIdx.x * 64 + threadIdx.x;
    if (t < N_GRAPHS * N_OUT) {
        int gph = t / N_OUT, o = t % N_OUT;
        float c = fmaxf(cnts[gph], 1.0f);
        float a = 0.f;
        for (int j = 0; j < HID; j++) a += sums[gph * 64 + j] * Wlin[j * N_OUT + o];
        out[t] = a / c + blin[o];
    }
}

extern "C" void kernel_launch(void* const* d_in, const int* in_sizes, int n_in,
                              void* d_out, int out_size, void* d_ws, size_t ws_size,
                              hipStream_t stream) {
    const float *x = nullptr, *W1 = nullptr, *W2 = nullptr, *W3 = nullptr, *Wlin = nullptr;
    const float *b1 = nullptr, *b2 = nullptr, *b3 = nullptr, *blin = nullptr;
    const int *ei = nullptr, *bat = nullptr;
    int n4096 = 0, n64 = 0;
    for (int i = 0; i < n_in; i++) {
        switch (in_sizes[i]) {
            case N_NODES * N_FEAT:  x    = (const float*)d_in[i]; break;
            case 2 * N_EDGES:       ei   = (const int*)d_in[i];   break;
            case N_NODES:           bat  = (const int*)d_in[i];   break;
            case N_FEAT * HID:      W1   = (const float*)d_in[i]; break;
            case HID * HID:
                if (n4096++ == 0) W2 = (const float*)d_in[i];
                else              W3 = (const float*)d_in[i];
                break;
            case HID * N_OUT:       Wlin = (const float*)d_in[i]; break;
            case HID:
                if (n64 == 0) b1 = (const float*)d_in[i];
                else if (n64 == 1) b2 = (const float*)d_in[i];
                else b3 = (const float*)d_in[i];
                n64++;
                break;
            case N_OUT:             blin = (const float*)d_in[i]; break;
            default: break;
        }
    }
    if (!x || !ei || !bat || !W1 || !W2 || !W3 || !Wlin || !b1 || !b2 || !b3 || !blin) {
        x    = (const float*)d_in[0];
        ei   = (const int*)d_in[1];
        bat  = (const int*)d_in[2];
        W1   = (const float*)d_in[3];  b1   = (const float*)d_in[4];
        W2   = (const float*)d_in[5];  b2   = (const float*)d_in[6];
        W3   = (const float*)d_in[7];  b3   = (const float*)d_in[8];
        Wlin = (const float*)d_in[9];  blin = (const float*)d_in[10];
    }
    float* out = (float*)d_out;  // fp32 output

    char* ws = (char*)d_ws;
    size_t off = 0;
    int2*           pairs = (int2*)(ws + off);           off += (size_t)NBUCK * CAP * 8;
    unsigned short* A     = (unsigned short*)(ws + off); off += (size_t)N_NODES * 64 * 2;
    unsigned char*  G     = (unsigned char*)(ws + off);  off += (size_t)(N_NODES + 1) * 64;
    float*          dis   = (float*)(ws + off);          off += (size_t)N_NODES * 4;
    float*          sums  = (float*)(ws + off);          off += (size_t)N_GRAPHS * HID * 4;
    float*          cnts  = (float*)(ws + off);          off += (size_t)N_GRAPHS * 4;
    int*            indeg = (int*)(ws + off);            off += (size_t)N_NODES * 4;
    int*            bcnt  = (int*)(ws + off);            off += NBUCK * 4;
    int*            incl  = (int*)(ws + off);            off += (size_t)N_NODES * 4;
    int*            offs  = (int*)(ws + off);            off += (size_t)N_NODES * 4;
    int*            bsum  = (int*)(ws + off);            off += 128 * 4;
    int*            srcs  = (int*)(ws + off);            off += (size_t)SRCS_CAP * 4;
    int*            flag  = (int*)(ws + off);            off += 4;

    const int nb_agg    = (N_NODES * 64 + 255) / 256;
    const int nb_bucket = (N_EDGES + 2047) / 2048;  // 782

    // detect + zero bcnt/sums/cnts (merged)
    k_detect<<<1, 256, 0, stream>>>(ei, flag, bcnt, sums, cnts);

    // --- CSR build: bucket -> per-bucket hist(+dis) -> scan -> place ---
    k_bucket<<<nb_bucket, 256, 0, stream>>>(ei, flag, pairs, bcnt);
    k_hist<<<NBUCK, 1024, 0, stream>>>(pairs, bcnt, indeg, dis);
    k_scan1<<<NBLK, SCAN_B, 0, stream>>>(indeg, incl, bsum);
    k_scan2<<<1, 128, 0, stream>>>(bsum);
    k_scan3<<<NBLK, SCAN_B, 0, stream>>>(indeg, incl, bsum, offs);
    k_place3<<<NBUCK, 1024, 0, stream>>>(pairs, bcnt, offs, srcs);

    // conv1: x(fp32,128) -> G(fp8) -> A(bf16)
    k_proj<128, float><<<512, 256, 0, stream>>>(x, W1, dis, G);
    k_agg<true><<<nb_agg, 256, 0, stream>>>(G, srcs, offs, indeg, dis, b1, A);

    // conv2: A -> G -> A
    k_proj<64, unsigned short><<<512, 256, 0, stream>>>(A, W2, dis, G);
    k_agg<true><<<nb_agg, 256, 0, stream>>>(G, srcs, offs, indeg, dis, b2, A);

    // conv3: A -> G -> A (no relu)
    k_proj<64, unsigned short><<<512, 256, 0, stream>>>(A, W3, dis, G);
    k_agg<false><<<nb_agg, 256, 0, stream>>>(G, srcs, offs, indeg, dis, b3, A);

    // pool + head (sums/cnts pre-zeroed in k_detect)
    k_pool<<<N_GRAPHS * 4, 256, 0, stream>>>(A, bat, flag, sums, cnts);
    k_head<<<(N_GRAPHS * N_OUT + 63) / 64, 64, 0, stream>>>(sums, cnts, Wlin, blin, out);
}